// Round 2
// baseline (1184.267 us; speedup 1.0000x reference)
//
#include <hip/hip_runtime.h>

// SimplifiedHAFE on MI355X — round 1: resubmit of round-0 kernel (infra
// failure, never ran). Structure: FE (2 matmul kernels) -> layer prep
// (lin/res matmuls + attention scalars) -> CSR build (count/scan/scatter,
// reused by both GAT layers) -> fully fused per-node GAT kernels (softmax +
// aggregate + residual + LN, no float atomics) -> classifier gather.

#define LRELU(x) ((x) > 0.f ? (x) : 0.2f * (x))

// ---------------------------------------------------------------- tiny tables
// aet1[t][h] = sum_d edge_emb1[t,d] * M1[d,h],
// M1[d,h] = sum_c lin_edge_w1[d,256][h*64+c] * att_edge1[h,c]   (layer 1, H=4)
// aet2[t]  likewise for layer 2 (H=1).
__global__ __launch_bounds__(64) void k_tables(
    const float* __restrict__ e_emb1, const float* __restrict__ lew1,
    const float* __restrict__ ae1,
    const float* __restrict__ e_emb2, const float* __restrict__ lew2,
    const float* __restrict__ ae2,
    float* __restrict__ aet1, float* __restrict__ aet2)
{
    __shared__ float M1[16];
    __shared__ float M2[4];
    int t = threadIdx.x;
    if (t < 16) {
        int d = t >> 2, h = t & 3;
        float s = 0.f;
        for (int c = 0; c < 64; ++c) s += lew1[d * 256 + h * 64 + c] * ae1[h * 64 + c];
        M1[d * 4 + h] = s;
    }
    if (t < 4) {
        float s = 0.f;
        for (int c = 0; c < 64; ++c) s += lew2[t * 64 + c] * ae2[c];
        M2[t] = s;
    }
    __syncthreads();
    if (t < 16) {
        int ty = t >> 2, h = t & 3;
        float s = 0.f;
        for (int d = 0; d < 4; ++d) s += e_emb1[ty * 4 + d] * M1[d * 4 + h];
        aet1[ty * 4 + h] = s;
    }
    if (t < 4) {
        float s = 0.f;
        for (int d = 0; d < 4; ++d) s += e_emb2[t * 4 + d] * M2[d];
        aet2[t] = s;
    }
}

// ------------------------------------------------- FE stage 1: relu(X@W1+b1)
// 16 rows/block staged in LDS; thread (r,c) accumulates rows r,r+4,r+8,r+12.
__global__ __launch_bounds__(256) void k_fe1(
    const float* __restrict__ feat, const float* __restrict__ w1,
    const float* __restrict__ b1, float* __restrict__ t1)
{
    __shared__ float lds[16 * 768];
    int t = threadIdx.x;
    long n0 = (long)blockIdx.x * 16;
    const float* fp = feat + n0 * 768;
    for (int idx = t; idx < 16 * 768; idx += 256) lds[idx] = fp[idx];
    __syncthreads();
    int r = t >> 6, c = t & 63;
    float a0 = 0.f, a1 = 0.f, a2 = 0.f, a3 = 0.f;
#pragma unroll 4
    for (int k = 0; k < 768; ++k) {
        float w = w1[k * 64 + c];
        a0 += lds[(r) * 768 + k] * w;
        a1 += lds[(r + 4) * 768 + k] * w;
        a2 += lds[(r + 8) * 768 + k] * w;
        a3 += lds[(r + 12) * 768 + k] * w;
    }
    float bb = b1[c];
    float* op = t1 + n0 * 64;
    op[(r) * 64 + c]      = fmaxf(a0 + bb, 0.f);
    op[(r + 4) * 64 + c]  = fmaxf(a1 + bb, 0.f);
    op[(r + 8) * 64 + c]  = fmaxf(a2 + bb, 0.f);
    op[(r + 12) * 64 + c] = fmaxf(a3 + bb, 0.f);
}

// ------------------------- FE tail: (@W2+b2 + emb + pos terms) @ out_w + b
__global__ __launch_bounds__(256) void k_fe2(
    const float* __restrict__ t1, const float* __restrict__ w2,
    const float* __restrict__ b2, const int* __restrict__ ntypes,
    const float* __restrict__ temb, const float* __restrict__ pos,
    const float* __restrict__ posw, const float* __restrict__ posb,
    const float* __restrict__ outw, const float* __restrict__ outb,
    float* __restrict__ hfe)
{
    __shared__ float l1[256];
    __shared__ float l2[256];
    int t = threadIdx.x;
    long base = (long)blockIdx.x * 256;  // 4 rows * 64
    l1[t] = t1[base + t];
    __syncthreads();
    int r = t >> 6, c = t & 63;
    float acc = 0.f;
#pragma unroll 8
    for (int k = 0; k < 64; ++k) acc += l1[r * 64 + k] * w2[k * 64 + c];
    long n = (long)blockIdx.x * 4 + r;
    int nt = ntypes[n];
    acc += b2[c] + temb[nt * 64 + c] + pos[n] * posw[c] + posb[c];
    l2[r * 64 + c] = acc;
    __syncthreads();
    float acc2 = 0.f;
#pragma unroll 8
    for (int k = 0; k < 64; ++k) acc2 += l2[r * 64 + k] * outw[k * 64 + c];
    hfe[n * 64 + c] = acc2 + outb[c];
}

// ------------- layer-1 prep: xs1 = hfe@lin_w, res_pre1 = bias+hfe@res_w+res_b
// plus per-(node,head) attention scalars a_src/a_dst via wave reductions.
__global__ __launch_bounds__(256) void k_prep1(
    const float* __restrict__ hfe, const float* __restrict__ lin_w,
    const float* __restrict__ res_w, const float* __restrict__ bias,
    const float* __restrict__ res_b, const float* __restrict__ att_s,
    const float* __restrict__ att_d, float* __restrict__ xs1,
    float* __restrict__ res_pre, float* __restrict__ a_src,
    float* __restrict__ a_dst)
{
    __shared__ float lh[512];
    int c = threadIdx.x;
    long n0 = (long)blockIdx.x * 8;
    for (int idx = c; idx < 512; idx += 256) lh[idx] = hfe[n0 * 64 + idx];
    __syncthreads();
    float ax[8], ar[8];
#pragma unroll
    for (int r = 0; r < 8; ++r) { ax[r] = 0.f; ar[r] = 0.f; }
    for (int k = 0; k < 64; ++k) {
        float wl = lin_w[k * 256 + c];
        float wr = res_w[k * 256 + c];
#pragma unroll
        for (int r = 0; r < 8; ++r) {
            float h = lh[r * 64 + k];
            ax[r] += h * wl;
            ar[r] += h * wr;
        }
    }
    float badd = bias[c] + res_b[c];
    float as = att_s[c], ad = att_d[c];  // att_[src|dst] flat [4,64] == [c]
    int hh = c >> 6, lane = c & 63;
#pragma unroll
    for (int r = 0; r < 8; ++r) {
        long n = n0 + r;
        xs1[n * 256 + c] = ax[r];
        res_pre[n * 256 + c] = ar[r] + badd;
        float p = ax[r] * as, q = ax[r] * ad;
#pragma unroll
        for (int k2 = 32; k2; k2 >>= 1) {
            p += __shfl_xor(p, k2, 64);
            q += __shfl_xor(q, k2, 64);
        }
        if (lane == 0) { a_src[n * 4 + hh] = p; a_dst[n * 4 + hh] = q; }
    }
}

// ---------------------------------------------------------------- CSR build
__global__ __launch_bounds__(256) void k_count(
    const int* __restrict__ dst, const int* __restrict__ et,
    int* __restrict__ cnt_t, int E)
{
    int e = blockIdx.x * 256 + threadIdx.x;
    if (e < E) atomicAdd(&cnt_t[dst[e] * 4 + et[e]], 1);
}

__global__ __launch_bounds__(256) void k_scan1(
    const int* __restrict__ cnt_t, int* __restrict__ row_off,
    int* __restrict__ blk_sums, int N)
{
    __shared__ int s[256];
    int t = threadIdx.x;
    int i = blockIdx.x * 256 + t;
    int v = 0;
    if (i < N) v = cnt_t[4 * i] + cnt_t[4 * i + 1] + cnt_t[4 * i + 2] + cnt_t[4 * i + 3];
    s[t] = v;
    __syncthreads();
    for (int off = 1; off < 256; off <<= 1) {
        int x = 0;
        if (t >= off) x = s[t - off];
        __syncthreads();
        s[t] += x;
        __syncthreads();
    }
    if (i < N) row_off[i] = s[t] - v;  // exclusive, partial
    if (t == 255) blk_sums[blockIdx.x] = s[255];
}

__global__ __launch_bounds__(256) void k_scan2(int* __restrict__ blk_sums, int nb)
{
    __shared__ int s[256];
    int t = threadIdx.x;
    int v = (t < nb) ? blk_sums[t] : 0;
    s[t] = v;
    __syncthreads();
    for (int off = 1; off < 256; off <<= 1) {
        int x = 0;
        if (t >= off) x = s[t - off];
        __syncthreads();
        s[t] += x;
        __syncthreads();
    }
    if (t < nb) blk_sums[t] = s[t] - v;  // exclusive, in place
}

__global__ __launch_bounds__(256) void k_scan3(
    int* __restrict__ row_off, int* __restrict__ cursor,
    const int* __restrict__ blk_sums, int N, int E)
{
    int t = threadIdx.x;
    int i = blockIdx.x * 256 + t;
    if (i < N) {
        int o = row_off[i] + blk_sums[blockIdx.x];
        row_off[i] = o;
        cursor[i] = o;
    }
    if (i == 0) row_off[N] = E;
}

__global__ __launch_bounds__(256) void k_scatter(
    const int* __restrict__ src, const int* __restrict__ dst,
    const int* __restrict__ et, int* __restrict__ cursor,
    int* __restrict__ csr_src, int* __restrict__ csr_et, int E)
{
    int e = blockIdx.x * 256 + threadIdx.x;
    if (e < E) {
        int d = dst[e];
        int pos = atomicAdd(&cursor[d], 1);
        csr_src[pos] = src[e];
        csr_et[pos] = et[e];
    }
}

// --------------------------- GAT layer 1: fused softmax+agg+residual+LN+ReLU
// block = 256 = 4 waves; wave h handles head h, lane = channel c.
// io: res_pre1 on input (own row read before write), hid1 on output.
__global__ __launch_bounds__(256) void k_gat1(
    const float* __restrict__ xs1, const float* __restrict__ a_src,
    const float* __restrict__ a_dst, const int* __restrict__ row_off,
    const int* __restrict__ csr_src, const int* __restrict__ csr_et,
    const int* __restrict__ cnt_t, const float* __restrict__ aet1,
    const float* __restrict__ ln_g, const float* __restrict__ ln_b,
    float* io)
{
    int n = blockIdx.x;
    int t = threadIdx.x;
    int h = t >> 6, c = t & 63;
    int off = row_off[n], deg = row_off[n + 1] - off;
    float a_s = a_src[n * 4 + h];
    float a_d = a_dst[n * 4 + h];
    // self-loop edge term: mean edge-attr collapses to type-count dot table
    float ael = 0.f;
    int degc = 0;
#pragma unroll
    for (int ty = 0; ty < 4; ++ty) {
        int ct = cnt_t[n * 4 + ty];
        degc += ct;
        ael += (float)ct * aet1[ty * 4 + h];
    }
    ael *= (degc > 0 ? 1.f / (float)degc : 1.f);
    float al = a_s + a_d + ael;
    al = LRELU(al);
    // pass 1: max over in-edges (+ self loop)
    float m = al;
    for (int i = c; i < deg; i += 64) {
        int s = csr_src[off + i];
        int ty = csr_et[off + i];
        float a = a_src[s * 4 + h] + a_d + aet1[ty * 4 + h];
        a = LRELU(a);
        m = fmaxf(m, a);
    }
#pragma unroll
    for (int k = 32; k; k >>= 1) m = fmaxf(m, __shfl_xor(m, k, 64));
    // pass 2: denom + weighted aggregate in one sweep (denom divides at end)
    float dsum = expf(al - m);
    float acc = dsum * xs1[n * 256 + h * 64 + c];
    for (int i = 0; i < deg; ++i) {
        int s = csr_src[off + i];
        int ty = csr_et[off + i];
        float a = a_src[s * 4 + h] + a_d + aet1[ty * 4 + h];
        a = LRELU(a);
        float ea = expf(a - m);
        dsum += ea;
        acc += ea * xs1[s * 256 + h * 64 + c];
    }
    float v = acc / (dsum + 1e-16f) + io[n * 256 + t];
    // LayerNorm over 256 + ReLU
    __shared__ float red[8];
    float s1 = v, s2 = v * v;
#pragma unroll
    for (int k = 32; k; k >>= 1) {
        s1 += __shfl_xor(s1, k, 64);
        s2 += __shfl_xor(s2, k, 64);
    }
    if (c == 0) { red[h] = s1; red[4 + h] = s2; }
    __syncthreads();
    float tot1 = red[0] + red[1] + red[2] + red[3];
    float tot2 = red[4] + red[5] + red[6] + red[7];
    float mu = tot1 * (1.f / 256.f);
    float var = tot2 * (1.f / 256.f) - mu * mu;
    float y = (v - mu) * rsqrtf(var + 1e-5f) * ln_g[t] + ln_b[t];
    io[n * 256 + t] = fmaxf(y, 0.f);
}

// ------------- layer-2 prep: xs2 = hid1@lin_w, res_pre2, a_src2/a_dst2 (H=1)
__global__ __launch_bounds__(256) void k_prep2(
    const float* __restrict__ hid1, const float* __restrict__ lin_w,
    const float* __restrict__ res_w, const float* __restrict__ bias,
    const float* __restrict__ res_b, const float* __restrict__ att_s,
    const float* __restrict__ att_d, float* __restrict__ xs2,
    float* __restrict__ res_pre, float* __restrict__ a_src,
    float* __restrict__ a_dst)
{
    __shared__ float lh[2048];
    int t = threadIdx.x;
    long n0 = (long)blockIdx.x * 8;
    for (int idx = t; idx < 2048; idx += 256) lh[idx] = hid1[n0 * 256 + idx];
    __syncthreads();
    int r = t >> 6, c = t & 63;
    float ax0 = 0.f, ar0 = 0.f, ax1 = 0.f, ar1 = 0.f;
    for (int k = 0; k < 256; ++k) {
        float wl = lin_w[k * 64 + c];
        float wr = res_w[k * 64 + c];
        float h0 = lh[r * 256 + k], h1 = lh[(r + 4) * 256 + k];
        ax0 += h0 * wl;
        ar0 += h0 * wr;
        ax1 += h1 * wl;
        ar1 += h1 * wr;
    }
    float badd = bias[c] + res_b[c];
    float as = att_s[c], ad = att_d[c];
    long na = n0 + r, nb2 = n0 + r + 4;
    xs2[na * 64 + c] = ax0;
    res_pre[na * 64 + c] = ar0 + badd;
    xs2[nb2 * 64 + c] = ax1;
    res_pre[nb2 * 64 + c] = ar1 + badd;
    float p0 = ax0 * as, q0 = ax0 * ad, p1 = ax1 * as, q1 = ax1 * ad;
#pragma unroll
    for (int k2 = 32; k2; k2 >>= 1) {
        p0 += __shfl_xor(p0, k2, 64);
        q0 += __shfl_xor(q0, k2, 64);
        p1 += __shfl_xor(p1, k2, 64);
        q1 += __shfl_xor(q1, k2, 64);
    }
    if (c == 0) { a_src[na] = p0; a_dst[na] = q0; a_src[nb2] = p1; a_dst[nb2] = q1; }
}

// --------------------------------- GAT layer 2 (H=1, C=64): one wave per node
__global__ __launch_bounds__(64) void k_gat2(
    const float* __restrict__ xs2, const float* __restrict__ a_src,
    const float* __restrict__ a_dst, const int* __restrict__ row_off,
    const int* __restrict__ csr_src, const int* __restrict__ csr_et,
    const int* __restrict__ cnt_t, const float* __restrict__ aet2,
    const float* __restrict__ ln_g, const float* __restrict__ ln_b,
    float* io)
{
    int n = blockIdx.x;
    int c = threadIdx.x;
    int off = row_off[n], deg = row_off[n + 1] - off;
    float a_s = a_src[n], a_d = a_dst[n];
    float ael = 0.f;
    int degc = 0;
#pragma unroll
    for (int ty = 0; ty < 4; ++ty) {
        int ct = cnt_t[n * 4 + ty];
        degc += ct;
        ael += (float)ct * aet2[ty];
    }
    ael *= (degc > 0 ? 1.f / (float)degc : 1.f);
    float al = a_s + a_d + ael;
    al = LRELU(al);
    float m = al;
    for (int i = c; i < deg; i += 64) {
        int s = csr_src[off + i];
        int ty = csr_et[off + i];
        float a = a_src[s] + a_d + aet2[ty];
        a = LRELU(a);
        m = fmaxf(m, a);
    }
#pragma unroll
    for (int k = 32; k; k >>= 1) m = fmaxf(m, __shfl_xor(m, k, 64));
    float dsum = expf(al - m);
    float acc = dsum * xs2[n * 64 + c];
    for (int i = 0; i < deg; ++i) {
        int s = csr_src[off + i];
        int ty = csr_et[off + i];
        float a = a_src[s] + a_d + aet2[ty];
        a = LRELU(a);
        float ea = expf(a - m);
        dsum += ea;
        acc += ea * xs2[s * 64 + c];
    }
    float v = acc / (dsum + 1e-16f) + io[n * 64 + c];
    float s1 = v, s2 = v * v;
#pragma unroll
    for (int k = 32; k; k >>= 1) {
        s1 += __shfl_xor(s1, k, 64);
        s2 += __shfl_xor(s2, k, 64);
    }
    float mu = s1 * (1.f / 64.f);
    float var = s2 * (1.f / 64.f) - mu * mu;
    io[n * 64 + c] = (v - mu) * rsqrtf(var + 1e-5f) * ln_g[c] + ln_b[c];
}

// --------------------------------------------------------------- classifier
__global__ __launch_bounds__(256) void k_cls(
    const float* __restrict__ hid2, const int* __restrict__ asp,
    const float* __restrict__ w, const float* __restrict__ b,
    float* __restrict__ out)
{
    int g = blockIdx.x * 256 + threadIdx.x;
    int i = g / 3, j = g - i * 3;
    int a = asp[i];
    float acc = b[j];
#pragma unroll 8
    for (int cc = 0; cc < 64; ++cc) acc += hid2[(long)a * 64 + cc] * w[cc * 3 + j];
    out[i * 3 + j] = acc;
}

extern "C" void kernel_launch(void* const* d_in, const int* in_sizes, int n_in,
                              void* d_out, int out_size, void* d_ws, size_t ws_size,
                              hipStream_t stream)
{
    const float* features    = (const float*)d_in[0];
    const int*   edge_index  = (const int*)d_in[1];
    const int*   aspect      = (const int*)d_in[2];
    const int*   etypes      = (const int*)d_in[3];
    const int*   ntypes      = (const int*)d_in[4];
    const float* pos         = (const float*)d_in[5];
    const float* fe_w1       = (const float*)d_in[6];
    const float* fe_b1       = (const float*)d_in[7];
    const float* fe_w2       = (const float*)d_in[8];
    const float* fe_b2       = (const float*)d_in[9];
    const float* fe_pos_w    = (const float*)d_in[10];
    const float* fe_pos_b    = (const float*)d_in[11];
    const float* fe_type_emb = (const float*)d_in[12];
    const float* fe_out_w    = (const float*)d_in[13];
    const float* fe_out_b    = (const float*)d_in[14];
    const float* g1_lin_w    = (const float*)d_in[15];
    const float* g1_att_src  = (const float*)d_in[16];
    const float* g1_att_dst  = (const float*)d_in[17];
    const float* g1_edge_emb = (const float*)d_in[18];
    const float* g1_lin_edge = (const float*)d_in[19];
    const float* g1_att_edge = (const float*)d_in[20];
    const float* g1_bias     = (const float*)d_in[21];
    const float* g1_res_w    = (const float*)d_in[22];
    const float* g1_res_b    = (const float*)d_in[23];
    const float* g1_ln_g     = (const float*)d_in[24];
    const float* g1_ln_b     = (const float*)d_in[25];
    const float* g2_lin_w    = (const float*)d_in[26];
    const float* g2_att_src  = (const float*)d_in[27];
    const float* g2_att_dst  = (const float*)d_in[28];
    const float* g2_edge_emb = (const float*)d_in[29];
    const float* g2_lin_edge = (const float*)d_in[30];
    const float* g2_att_edge = (const float*)d_in[31];
    const float* g2_bias     = (const float*)d_in[32];
    const float* g2_res_w    = (const float*)d_in[33];
    const float* g2_res_b    = (const float*)d_in[34];
    const float* g2_ln_g     = (const float*)d_in[35];
    const float* g2_ln_b     = (const float*)d_in[36];
    const float* cls_w       = (const float*)d_in[37];
    const float* cls_b       = (const float*)d_in[38];

    const int N = in_sizes[0] / 768;   // 50000
    const int E = in_sizes[1] / 2;     // 800000
    const int* src = edge_index;
    const int* dst = edge_index + E;

    char* wsb = (char*)d_ws;
    size_t off = 0;
    auto alloc = [&](size_t bytes) -> char* {
        char* p = wsb + off;
        off += (bytes + 255) & ~(size_t)255;
        return p;
    };
    float* t1      = (float*)alloc((size_t)N * 64 * 4);   // FE stage-1; reused as xs2
    float* hfe     = (float*)alloc((size_t)N * 64 * 4);
    float* xs1     = (float*)alloc((size_t)N * 256 * 4);
    float* rp1     = (float*)alloc((size_t)N * 256 * 4);  // res_pre1, then hid1
    float* rp2     = (float*)alloc((size_t)N * 64 * 4);   // res_pre2, then hid2
    float* a_src1  = (float*)alloc((size_t)N * 4 * 4);
    float* a_dst1  = (float*)alloc((size_t)N * 4 * 4);
    float* a_src2  = (float*)alloc((size_t)N * 4);
    float* a_dst2  = (float*)alloc((size_t)N * 4);
    int*   cnt_t   = (int*)alloc((size_t)N * 4 * 4);
    int*   row_off = (int*)alloc((size_t)(N + 1) * 4);
    int*   cursor  = (int*)alloc((size_t)N * 4);
    int*   blk     = (int*)alloc(1024);
    int*   csr_src = (int*)alloc((size_t)E * 4);
    int*   csr_et  = (int*)alloc((size_t)E * 4);
    float* aet1    = (float*)alloc(64);
    float* aet2    = (float*)alloc(64);
    float* xs2     = t1;

    hipMemsetAsync(cnt_t, 0, (size_t)N * 4 * 4, stream);

    k_tables<<<1, 64, 0, stream>>>(g1_edge_emb, g1_lin_edge, g1_att_edge,
                                   g2_edge_emb, g2_lin_edge, g2_att_edge, aet1, aet2);
    k_fe1<<<N / 16, 256, 0, stream>>>(features, fe_w1, fe_b1, t1);
    k_fe2<<<N / 4, 256, 0, stream>>>(t1, fe_w2, fe_b2, ntypes, fe_type_emb, pos,
                                     fe_pos_w, fe_pos_b, fe_out_w, fe_out_b, hfe);
    k_prep1<<<N / 8, 256, 0, stream>>>(hfe, g1_lin_w, g1_res_w, g1_bias, g1_res_b,
                                       g1_att_src, g1_att_dst, xs1, rp1, a_src1, a_dst1);
    int eblk = (E + 255) / 256;
    int nb = (N + 255) / 256;
    k_count<<<eblk, 256, 0, stream>>>(dst, etypes, cnt_t, E);
    k_scan1<<<nb, 256, 0, stream>>>(cnt_t, row_off, blk, N);
    k_scan2<<<1, 256, 0, stream>>>(blk, nb);
    k_scan3<<<nb, 256, 0, stream>>>(row_off, cursor, blk, N, E);
    k_scatter<<<eblk, 256, 0, stream>>>(src, dst, etypes, cursor, csr_src, csr_et, E);
    k_gat1<<<N, 256, 0, stream>>>(xs1, a_src1, a_dst1, row_off, csr_src, csr_et,
                                  cnt_t, aet1, g1_ln_g, g1_ln_b, rp1);
    k_prep2<<<N / 8, 256, 0, stream>>>(rp1, g2_lin_w, g2_res_w, g2_bias, g2_res_b,
                                       g2_att_src, g2_att_dst, xs2, rp2, a_src2, a_dst2);
    k_gat2<<<N, 64, 0, stream>>>(xs2, a_src2, a_dst2, row_off, csr_src, csr_et,
                                 cnt_t, aet2, g2_ln_g, g2_ln_b, rp2);
    k_cls<<<(out_size + 255) / 256, 256, 0, stream>>>(rp2, aspect, cls_w, cls_b,
                                                      (float*)d_out);
}

// Round 3
// 976.461 us; speedup vs baseline: 1.2128x; 1.2128x over previous
//
#include <hip/hip_runtime.h>

// SimplifiedHAFE on MI355X — round 2: k_fe1 rewritten as bf16 MFMA GEMM.
// Round-1 profile: k_fe1 = 303 us, LDS-throughput-bound (4 ds_read_b32 per
// 4 FMAs; 38.4M wave ds-instr ~= 360 us model). New k_fe1: 16x16x32 bf16
// MFMA, 64x64 block tile, K-chunk 64, fragment-order LDS layout (every frag
// read = 1 ds_read_b128), fp32->bf16 RNE fused into staging.
// Everything else unchanged from round 1.

#define LRELU(x) ((x) > 0.f ? (x) : 0.2f * (x))

typedef __attribute__((ext_vector_type(8))) short short8;
typedef __attribute__((ext_vector_type(4))) float floatx4;

__device__ __forceinline__ unsigned short f2bf(float x) {
    union { float f; unsigned int u; } v; v.f = x;
    unsigned int r = (v.u + 0x7FFFu + ((v.u >> 16) & 1u)) >> 16;  // RNE
    return (unsigned short)r;
}

// ---------------------------------------------------------------- tiny tables
__global__ __launch_bounds__(64) void k_tables(
    const float* __restrict__ e_emb1, const float* __restrict__ lew1,
    const float* __restrict__ ae1,
    const float* __restrict__ e_emb2, const float* __restrict__ lew2,
    const float* __restrict__ ae2,
    float* __restrict__ aet1, float* __restrict__ aet2)
{
    __shared__ float M1[16];
    __shared__ float M2[4];
    int t = threadIdx.x;
    if (t < 16) {
        int d = t >> 2, h = t & 3;
        float s = 0.f;
        for (int c = 0; c < 64; ++c) s += lew1[d * 256 + h * 64 + c] * ae1[h * 64 + c];
        M1[d * 4 + h] = s;
    }
    if (t < 4) {
        float s = 0.f;
        for (int c = 0; c < 64; ++c) s += lew2[t * 64 + c] * ae2[c];
        M2[t] = s;
    }
    __syncthreads();
    if (t < 16) {
        int ty = t >> 2, h = t & 3;
        float s = 0.f;
        for (int d = 0; d < 4; ++d) s += e_emb1[ty * 4 + d] * M1[d * 4 + h];
        aet1[ty * 4 + h] = s;
    }
    if (t < 4) {
        float s = 0.f;
        for (int d = 0; d < 4; ++d) s += e_emb2[t * 4 + d] * M2[d];
        aet2[t] = s;
    }
}

// ------------------------------------- FE stage 1: relu(X@W1+b1), bf16 MFMA
// Block: 256 thr = 4 waves. Tile M=64 rows x N=64 cols; wave w -> cols
// [16w,16w+16), 4 M-tiles each. K-chunk 64 (2 mfma k-steps of 32).
// LDS layout (fragment order): X_lds[kg][m][j] so each A/B frag is one
// contiguous 16B ds_read_b128 (kg = k/8 within chunk, j = k%8).
__global__ __launch_bounds__(256) void k_fe1(
    const float* __restrict__ feat, const float* __restrict__ w1,
    const float* __restrict__ b1, float* __restrict__ t1, int N)
{
    __shared__ __align__(16) unsigned short A_lds[8 * 64 * 8];  // 8 KiB
    __shared__ __align__(16) unsigned short B_lds[8 * 64 * 8];  // 8 KiB
    int t = threadIdx.x;
    int wv = t >> 6, lane = t & 63;
    int quad = lane >> 4, l16 = lane & 15;
    long n0 = (long)blockIdx.x * 64;

    floatx4 acc[4];
#pragma unroll
    for (int i = 0; i < 4; ++i) acc[i] = (floatx4){0.f, 0.f, 0.f, 0.f};

    // staging mapping: thread -> (row t>>2, float4 lane t&3 stepped by 4)
    int srow = t >> 2;
    int sf4 = t & 3;
    long arow = n0 + srow;
    if (arow >= N) arow = N - 1;           // clamp tail loads (outputs guarded)
    const float* fbase = feat + arow * 768;

    for (int kc = 0; kc < 768; kc += 64) {
        __syncthreads();  // previous chunk's frag reads done before restage
        // ---- stage A (64 rows x 64 k): fp32 -> bf16, fragment-order
#pragma unroll
        for (int i = 0; i < 4; ++i) {
            int f = sf4 + i * 4;           // float4 index in row, 0..15
            int kl = f * 4;                // k_local, multiple of 4
            float4 v = *(const float4*)(fbase + kc + kl);
            int kg = kl >> 3, ko = kl & 7; // ko in {0,4}
            unsigned short* d = &A_lds[(kg * 64 + srow) * 8 + ko];
            ushort4 pk = {f2bf(v.x), f2bf(v.y), f2bf(v.z), f2bf(v.w)};
            *(ushort4*)d = pk;             // 8B aligned store
        }
        // ---- stage B (64 k x 64 n): fp32 -> bf16, scatter into frag order
#pragma unroll
        for (int i = 0; i < 4; ++i) {
            int f = sf4 + i * 4;
            int nl = f * 4;                // col base
            int kl = srow;                 // k row
            float4 v = *(const float4*)(w1 + (long)(kc + kl) * 64 + nl);
            int kg = kl >> 3, j = kl & 7;
            B_lds[(kg * 64 + nl + 0) * 8 + j] = f2bf(v.x);
            B_lds[(kg * 64 + nl + 1) * 8 + j] = f2bf(v.y);
            B_lds[(kg * 64 + nl + 2) * 8 + j] = f2bf(v.z);
            B_lds[(kg * 64 + nl + 3) * 8 + j] = f2bf(v.w);
        }
        __syncthreads();
        // ---- 2 mfma k-steps of 32
#pragma unroll
        for (int s = 0; s < 2; ++s) {
            int kg0 = s * 4 + quad;
            short8 bfrag = *(const short8*)&B_lds[(kg0 * 64 + wv * 16 + l16) * 8];
#pragma unroll
            for (int mt = 0; mt < 4; ++mt) {
                short8 afrag = *(const short8*)&A_lds[(kg0 * 64 + mt * 16 + l16) * 8];
                acc[mt] = __builtin_amdgcn_mfma_f32_16x16x32_bf16(
                    afrag, bfrag, acc[mt], 0, 0, 0);
            }
        }
    }
    // ---- epilogue: bias + relu; C layout col=lane&15, row=quad*4+reg
    int col = wv * 16 + l16;
    float bb = b1[col];
#pragma unroll
    for (int mt = 0; mt < 4; ++mt) {
#pragma unroll
        for (int r = 0; r < 4; ++r) {
            long m = n0 + mt * 16 + quad * 4 + r;
            if (m < N) t1[m * 64 + col] = fmaxf(acc[mt][r] + bb, 0.f);
        }
    }
}

// ------------------------- FE tail: (@W2+b2 + emb + pos terms) @ out_w + b
__global__ __launch_bounds__(256) void k_fe2(
    const float* __restrict__ t1, const float* __restrict__ w2,
    const float* __restrict__ b2, const int* __restrict__ ntypes,
    const float* __restrict__ temb, const float* __restrict__ pos,
    const float* __restrict__ posw, const float* __restrict__ posb,
    const float* __restrict__ outw, const float* __restrict__ outb,
    float* __restrict__ hfe)
{
    __shared__ float l1[256];
    __shared__ float l2[256];
    int t = threadIdx.x;
    long base = (long)blockIdx.x * 256;  // 4 rows * 64
    l1[t] = t1[base + t];
    __syncthreads();
    int r = t >> 6, c = t & 63;
    float acc = 0.f;
#pragma unroll 8
    for (int k = 0; k < 64; ++k) acc += l1[r * 64 + k] * w2[k * 64 + c];
    long n = (long)blockIdx.x * 4 + r;
    int nt = ntypes[n];
    acc += b2[c] + temb[nt * 64 + c] + pos[n] * posw[c] + posb[c];
    l2[r * 64 + c] = acc;
    __syncthreads();
    float acc2 = 0.f;
#pragma unroll 8
    for (int k = 0; k < 64; ++k) acc2 += l2[r * 64 + k] * outw[k * 64 + c];
    hfe[n * 64 + c] = acc2 + outb[c];
}

// ------------- layer-1 prep: xs1 = hfe@lin_w, res_pre1 = bias+hfe@res_w+res_b
__global__ __launch_bounds__(256) void k_prep1(
    const float* __restrict__ hfe, const float* __restrict__ lin_w,
    const float* __restrict__ res_w, const float* __restrict__ bias,
    const float* __restrict__ res_b, const float* __restrict__ att_s,
    const float* __restrict__ att_d, float* __restrict__ xs1,
    float* __restrict__ res_pre, float* __restrict__ a_src,
    float* __restrict__ a_dst)
{
    __shared__ float lh[512];
    int c = threadIdx.x;
    long n0 = (long)blockIdx.x * 8;
    for (int idx = c; idx < 512; idx += 256) lh[idx] = hfe[n0 * 64 + idx];
    __syncthreads();
    float ax[8], ar[8];
#pragma unroll
    for (int r = 0; r < 8; ++r) { ax[r] = 0.f; ar[r] = 0.f; }
    for (int k = 0; k < 64; ++k) {
        float wl = lin_w[k * 256 + c];
        float wr = res_w[k * 256 + c];
#pragma unroll
        for (int r = 0; r < 8; ++r) {
            float h = lh[r * 64 + k];
            ax[r] += h * wl;
            ar[r] += h * wr;
        }
    }
    float badd = bias[c] + res_b[c];
    float as = att_s[c], ad = att_d[c];
    int hh = c >> 6, lane = c & 63;
#pragma unroll
    for (int r = 0; r < 8; ++r) {
        long n = n0 + r;
        xs1[n * 256 + c] = ax[r];
        res_pre[n * 256 + c] = ar[r] + badd;
        float p = ax[r] * as, q = ax[r] * ad;
#pragma unroll
        for (int k2 = 32; k2; k2 >>= 1) {
            p += __shfl_xor(p, k2, 64);
            q += __shfl_xor(q, k2, 64);
        }
        if (lane == 0) { a_src[n * 4 + hh] = p; a_dst[n * 4 + hh] = q; }
    }
}

// ---------------------------------------------------------------- CSR build
__global__ __launch_bounds__(256) void k_count(
    const int* __restrict__ dst, const int* __restrict__ et,
    int* __restrict__ cnt_t, int E)
{
    int e = blockIdx.x * 256 + threadIdx.x;
    if (e < E) atomicAdd(&cnt_t[dst[e] * 4 + et[e]], 1);
}

__global__ __launch_bounds__(256) void k_scan1(
    const int* __restrict__ cnt_t, int* __restrict__ row_off,
    int* __restrict__ blk_sums, int N)
{
    __shared__ int s[256];
    int t = threadIdx.x;
    int i = blockIdx.x * 256 + t;
    int v = 0;
    if (i < N) v = cnt_t[4 * i] + cnt_t[4 * i + 1] + cnt_t[4 * i + 2] + cnt_t[4 * i + 3];
    s[t] = v;
    __syncthreads();
    for (int off = 1; off < 256; off <<= 1) {
        int x = 0;
        if (t >= off) x = s[t - off];
        __syncthreads();
        s[t] += x;
        __syncthreads();
    }
    if (i < N) row_off[i] = s[t] - v;
    if (t == 255) blk_sums[blockIdx.x] = s[255];
}

__global__ __launch_bounds__(256) void k_scan2(int* __restrict__ blk_sums, int nb)
{
    __shared__ int s[256];
    int t = threadIdx.x;
    int v = (t < nb) ? blk_sums[t] : 0;
    s[t] = v;
    __syncthreads();
    for (int off = 1; off < 256; off <<= 1) {
        int x = 0;
        if (t >= off) x = s[t - off];
        __syncthreads();
        s[t] += x;
        __syncthreads();
    }
    if (t < nb) blk_sums[t] = s[t] - v;
}

__global__ __launch_bounds__(256) void k_scan3(
    int* __restrict__ row_off, int* __restrict__ cursor,
    const int* __restrict__ blk_sums, int N, int E)
{
    int t = threadIdx.x;
    int i = blockIdx.x * 256 + t;
    if (i < N) {
        int o = row_off[i] + blk_sums[blockIdx.x];
        row_off[i] = o;
        cursor[i] = o;
    }
    if (i == 0) row_off[N] = E;
}

__global__ __launch_bounds__(256) void k_scatter(
    const int* __restrict__ src, const int* __restrict__ dst,
    const int* __restrict__ et, int* __restrict__ cursor,
    int* __restrict__ csr_src, int* __restrict__ csr_et, int E)
{
    int e = blockIdx.x * 256 + threadIdx.x;
    if (e < E) {
        int d = dst[e];
        int pos = atomicAdd(&cursor[d], 1);
        csr_src[pos] = src[e];
        csr_et[pos] = et[e];
    }
}

// --------------------------- GAT layer 1: fused softmax+agg+residual+LN+ReLU
__global__ __launch_bounds__(256) void k_gat1(
    const float* __restrict__ xs1, const float* __restrict__ a_src,
    const float* __restrict__ a_dst, const int* __restrict__ row_off,
    const int* __restrict__ csr_src, const int* __restrict__ csr_et,
    const int* __restrict__ cnt_t, const float* __restrict__ aet1,
    const float* __restrict__ ln_g, const float* __restrict__ ln_b,
    float* io)
{
    int n = blockIdx.x;
    int t = threadIdx.x;
    int h = t >> 6, c = t & 63;
    int off = row_off[n], deg = row_off[n + 1] - off;
    float a_s = a_src[n * 4 + h];
    float a_d = a_dst[n * 4 + h];
    float ael = 0.f;
    int degc = 0;
#pragma unroll
    for (int ty = 0; ty < 4; ++ty) {
        int ct = cnt_t[n * 4 + ty];
        degc += ct;
        ael += (float)ct * aet1[ty * 4 + h];
    }
    ael *= (degc > 0 ? 1.f / (float)degc : 1.f);
    float al = a_s + a_d + ael;
    al = LRELU(al);
    float m = al;
    for (int i = c; i < deg; i += 64) {
        int s = csr_src[off + i];
        int ty = csr_et[off + i];
        float a = a_src[s * 4 + h] + a_d + aet1[ty * 4 + h];
        a = LRELU(a);
        m = fmaxf(m, a);
    }
#pragma unroll
    for (int k = 32; k; k >>= 1) m = fmaxf(m, __shfl_xor(m, k, 64));
    float dsum = expf(al - m);
    float acc = dsum * xs1[n * 256 + h * 64 + c];
    for (int i = 0; i < deg; ++i) {
        int s = csr_src[off + i];
        int ty = csr_et[off + i];
        float a = a_src[s * 4 + h] + a_d + aet1[ty * 4 + h];
        a = LRELU(a);
        float ea = expf(a - m);
        dsum += ea;
        acc += ea * xs1[s * 256 + h * 64 + c];
    }
    float v = acc / (dsum + 1e-16f) + io[n * 256 + t];
    __shared__ float red[8];
    float s1 = v, s2 = v * v;
#pragma unroll
    for (int k = 32; k; k >>= 1) {
        s1 += __shfl_xor(s1, k, 64);
        s2 += __shfl_xor(s2, k, 64);
    }
    if (c == 0) { red[h] = s1; red[4 + h] = s2; }
    __syncthreads();
    float tot1 = red[0] + red[1] + red[2] + red[3];
    float tot2 = red[4] + red[5] + red[6] + red[7];
    float mu = tot1 * (1.f / 256.f);
    float var = tot2 * (1.f / 256.f) - mu * mu;
    float y = (v - mu) * rsqrtf(var + 1e-5f) * ln_g[t] + ln_b[t];
    io[n * 256 + t] = fmaxf(y, 0.f);
}

// ------------- layer-2 prep: xs2 = hid1@lin_w, res_pre2, a_src2/a_dst2 (H=1)
__global__ __launch_bounds__(256) void k_prep2(
    const float* __restrict__ hid1, const float* __restrict__ lin_w,
    const float* __restrict__ res_w, const float* __restrict__ bias,
    const float* __restrict__ res_b, const float* __restrict__ att_s,
    const float* __restrict__ att_d, float* __restrict__ xs2,
    float* __restrict__ res_pre, float* __restrict__ a_src,
    float* __restrict__ a_dst)
{
    __shared__ float lh[2048];
    int t = threadIdx.x;
    long n0 = (long)blockIdx.x * 8;
    for (int idx = t; idx < 2048; idx += 256) lh[idx] = hid1[n0 * 256 + idx];
    __syncthreads();
    int r = t >> 6, c = t & 63;
    float ax0 = 0.f, ar0 = 0.f, ax1 = 0.f, ar1 = 0.f;
    for (int k = 0; k < 256; ++k) {
        float wl = lin_w[k * 64 + c];
        float wr = res_w[k * 64 + c];
        float h0 = lh[r * 256 + k], h1 = lh[(r + 4) * 256 + k];
        ax0 += h0 * wl;
        ar0 += h0 * wr;
        ax1 += h1 * wl;
        ar1 += h1 * wr;
    }
    float badd = bias[c] + res_b[c];
    float as = att_s[c], ad = att_d[c];
    long na = n0 + r, nb2 = n0 + r + 4;
    xs2[na * 64 + c] = ax0;
    res_pre[na * 64 + c] = ar0 + badd;
    xs2[nb2 * 64 + c] = ax1;
    res_pre[nb2 * 64 + c] = ar1 + badd;
    float p0 = ax0 * as, q0 = ax0 * ad, p1 = ax1 * as, q1 = ax1 * ad;
#pragma unroll
    for (int k2 = 32; k2; k2 >>= 1) {
        p0 += __shfl_xor(p0, k2, 64);
        q0 += __shfl_xor(q0, k2, 64);
        p1 += __shfl_xor(p1, k2, 64);
        q1 += __shfl_xor(q1, k2, 64);
    }
    if (c == 0) { a_src[na] = p0; a_dst[na] = q0; a_src[nb2] = p1; a_dst[nb2] = q1; }
}

// --------------------------------- GAT layer 2 (H=1, C=64): one wave per node
__global__ __launch_bounds__(64) void k_gat2(
    const float* __restrict__ xs2, const float* __restrict__ a_src,
    const float* __restrict__ a_dst, const int* __restrict__ row_off,
    const int* __restrict__ csr_src, const int* __restrict__ csr_et,
    const int* __restrict__ cnt_t, const float* __restrict__ aet2,
    const float* __restrict__ ln_g, const float* __restrict__ ln_b,
    float* io)
{
    int n = blockIdx.x;
    int c = threadIdx.x;
    int off = row_off[n], deg = row_off[n + 1] - off;
    float a_s = a_src[n], a_d = a_dst[n];
    float ael = 0.f;
    int degc = 0;
#pragma unroll
    for (int ty = 0; ty < 4; ++ty) {
        int ct = cnt_t[n * 4 + ty];
        degc += ct;
        ael += (float)ct * aet2[ty];
    }
    ael *= (degc > 0 ? 1.f / (float)degc : 1.f);
    float al = a_s + a_d + ael;
    al = LRELU(al);
    float m = al;
    for (int i = c; i < deg; i += 64) {
        int s = csr_src[off + i];
        int ty = csr_et[off + i];
        float a = a_src[s] + a_d + aet2[ty];
        a = LRELU(a);
        m = fmaxf(m, a);
    }
#pragma unroll
    for (int k = 32; k; k >>= 1) m = fmaxf(m, __shfl_xor(m, k, 64));
    float dsum = expf(al - m);
    float acc = dsum * xs2[n * 64 + c];
    for (int i = 0; i < deg; ++i) {
        int s = csr_src[off + i];
        int ty = csr_et[off + i];
        float a = a_src[s] + a_d + aet2[ty];
        a = LRELU(a);
        float ea = expf(a - m);
        dsum += ea;
        acc += ea * xs2[s * 64 + c];
    }
    float v = acc / (dsum + 1e-16f) + io[n * 64 + c];
    float s1 = v, s2 = v * v;
#pragma unroll
    for (int k = 32; k; k >>= 1) {
        s1 += __shfl_xor(s1, k, 64);
        s2 += __shfl_xor(s2, k, 64);
    }
    float mu = s1 * (1.f / 64.f);
    float var = s2 * (1.f / 64.f) - mu * mu;
    io[n * 64 + c] = (v - mu) * rsqrtf(var + 1e-5f) * ln_g[c] + ln_b[c];
}

// --------------------------------------------------------------- classifier
__global__ __launch_bounds__(256) void k_cls(
    const float* __restrict__ hid2, const int* __restrict__ asp,
    const float* __restrict__ w, const float* __restrict__ b,
    float* __restrict__ out)
{
    int g = blockIdx.x * 256 + threadIdx.x;
    int i = g / 3, j = g - i * 3;
    int a = asp[i];
    float acc = b[j];
#pragma unroll 8
    for (int cc = 0; cc < 64; ++cc) acc += hid2[(long)a * 64 + cc] * w[cc * 3 + j];
    out[i * 3 + j] = acc;
}

extern "C" void kernel_launch(void* const* d_in, const int* in_sizes, int n_in,
                              void* d_out, int out_size, void* d_ws, size_t ws_size,
                              hipStream_t stream)
{
    const float* features    = (const float*)d_in[0];
    const int*   edge_index  = (const int*)d_in[1];
    const int*   aspect      = (const int*)d_in[2];
    const int*   etypes      = (const int*)d_in[3];
    const int*   ntypes      = (const int*)d_in[4];
    const float* pos         = (const float*)d_in[5];
    const float* fe_w1       = (const float*)d_in[6];
    const float* fe_b1       = (const float*)d_in[7];
    const float* fe_w2       = (const float*)d_in[8];
    const float* fe_b2       = (const float*)d_in[9];
    const float* fe_pos_w    = (const float*)d_in[10];
    const float* fe_pos_b    = (const float*)d_in[11];
    const float* fe_type_emb = (const float*)d_in[12];
    const float* fe_out_w    = (const float*)d_in[13];
    const float* fe_out_b    = (const float*)d_in[14];
    const float* g1_lin_w    = (const float*)d_in[15];
    const float* g1_att_src  = (const float*)d_in[16];
    const float* g1_att_dst  = (const float*)d_in[17];
    const float* g1_edge_emb = (const float*)d_in[18];
    const float* g1_lin_edge = (const float*)d_in[19];
    const float* g1_att_edge = (const float*)d_in[20];
    const float* g1_bias     = (const float*)d_in[21];
    const float* g1_res_w    = (const float*)d_in[22];
    const float* g1_res_b    = (const float*)d_in[23];
    const float* g1_ln_g     = (const float*)d_in[24];
    const float* g1_ln_b     = (const float*)d_in[25];
    const float* g2_lin_w    = (const float*)d_in[26];
    const float* g2_att_src  = (const float*)d_in[27];
    const float* g2_att_dst  = (const float*)d_in[28];
    const float* g2_edge_emb = (const float*)d_in[29];
    const float* g2_lin_edge = (const float*)d_in[30];
    const float* g2_att_edge = (const float*)d_in[31];
    const float* g2_bias     = (const float*)d_in[32];
    const float* g2_res_w    = (const float*)d_in[33];
    const float* g2_res_b    = (const float*)d_in[34];
    const float* g2_ln_g     = (const float*)d_in[35];
    const float* g2_ln_b     = (const float*)d_in[36];
    const float* cls_w       = (const float*)d_in[37];
    const float* cls_b       = (const float*)d_in[38];

    const int N = in_sizes[0] / 768;   // 50000
    const int E = in_sizes[1] / 2;     // 800000
    const int* src = edge_index;
    const int* dst = edge_index + E;

    char* wsb = (char*)d_ws;
    size_t off = 0;
    auto alloc = [&](size_t bytes) -> char* {
        char* p = wsb + off;
        off += (bytes + 255) & ~(size_t)255;
        return p;
    };
    float* t1      = (float*)alloc((size_t)N * 64 * 4);   // FE stage-1; reused as xs2
    float* hfe     = (float*)alloc((size_t)N * 64 * 4);
    float* xs1     = (float*)alloc((size_t)N * 256 * 4);
    float* rp1     = (float*)alloc((size_t)N * 256 * 4);  // res_pre1, then hid1
    float* rp2     = (float*)alloc((size_t)N * 64 * 4);   // res_pre2, then hid2
    float* a_src1  = (float*)alloc((size_t)N * 4 * 4);
    float* a_dst1  = (float*)alloc((size_t)N * 4 * 4);
    float* a_src2  = (float*)alloc((size_t)N * 4);
    float* a_dst2  = (float*)alloc((size_t)N * 4);
    int*   cnt_t   = (int*)alloc((size_t)N * 4 * 4);
    int*   row_off = (int*)alloc((size_t)(N + 1) * 4);
    int*   cursor  = (int*)alloc((size_t)N * 4);
    int*   blk     = (int*)alloc(1024);
    int*   csr_src = (int*)alloc((size_t)E * 4);
    int*   csr_et  = (int*)alloc((size_t)E * 4);
    float* aet1    = (float*)alloc(64);
    float* aet2    = (float*)alloc(64);
    float* xs2     = t1;

    hipMemsetAsync(cnt_t, 0, (size_t)N * 4 * 4, stream);

    k_tables<<<1, 64, 0, stream>>>(g1_edge_emb, g1_lin_edge, g1_att_edge,
                                   g2_edge_emb, g2_lin_edge, g2_att_edge, aet1, aet2);
    k_fe1<<<(N + 63) / 64, 256, 0, stream>>>(features, fe_w1, fe_b1, t1, N);
    k_fe2<<<N / 4, 256, 0, stream>>>(t1, fe_w2, fe_b2, ntypes, fe_type_emb, pos,
                                     fe_pos_w, fe_pos_b, fe_out_w, fe_out_b, hfe);
    k_prep1<<<N / 8, 256, 0, stream>>>(hfe, g1_lin_w, g1_res_w, g1_bias, g1_res_b,
                                       g1_att_src, g1_att_dst, xs1, rp1, a_src1, a_dst1);
    int eblk = (E + 255) / 256;
    int nb = (N + 255) / 256;
    k_count<<<eblk, 256, 0, stream>>>(dst, etypes, cnt_t, E);
    k_scan1<<<nb, 256, 0, stream>>>(cnt_t, row_off, blk, N);
    k_scan2<<<1, 256, 0, stream>>>(blk, nb);
    k_scan3<<<nb, 256, 0, stream>>>(row_off, cursor, blk, N, E);
    k_scatter<<<eblk, 256, 0, stream>>>(src, dst, etypes, cursor, csr_src, csr_et, E);
    k_gat1<<<N, 256, 0, stream>>>(xs1, a_src1, a_dst1, row_off, csr_src, csr_et,
                                  cnt_t, aet1, g1_ln_g, g1_ln_b, rp1);
    k_prep2<<<N / 8, 256, 0, stream>>>(rp1, g2_lin_w, g2_res_w, g2_bias, g2_res_b,
                                       g2_att_src, g2_att_dst, xs2, rp2, a_src2, a_dst2);
    k_gat2<<<N, 64, 0, stream>>>(xs2, a_src2, a_dst2, row_off, csr_src, csr_et,
                                 cnt_t, aet2, g2_ln_g, g2_ln_b, rp2);
    k_cls<<<(out_size + 255) / 256, 256, 0, stream>>>(rp2, aspect, cls_w, cls_b,
                                                      (float*)d_out);
}

// Round 4
// 872.498 us; speedup vs baseline: 1.3573x; 1.1192x over previous
//
#include <hip/hip_runtime.h>

// SimplifiedHAFE on MI355X — round 3: GAT edge loops restructured.
// Round-2 profile: k_gat1 = 255 us, VALUBusy 87%, HBM 26% — serial per-edge
// scalar chain (gather a_src -> lrelu -> expf) on the wave-uniform critical
// path, ~196 cyc/edge-iter. New structure: chunk-of-64 lane-parallel weight
// computation (one edge per lane: alpha/exp in parallel, packed (w,src) float2
// into wave-private LDS), then aggregation loop = ds_read_b64 broadcast +
// coalesced 256B gather + fma, 4-way unrolled. CSR packs (src | ty<<28).
// k_gat2 gets the identical restructure. fe1 stays bf16 MFMA (round-2 win).

#define LRELU(x) ((x) > 0.f ? (x) : 0.2f * (x))

typedef __attribute__((ext_vector_type(8))) short short8;
typedef __attribute__((ext_vector_type(4))) float floatx4;

__device__ __forceinline__ unsigned short f2bf(float x) {
    union { float f; unsigned int u; } v; v.f = x;
    unsigned int r = (v.u + 0x7FFFu + ((v.u >> 16) & 1u)) >> 16;  // RNE
    return (unsigned short)r;
}

// ---------------------------------------------------------------- tiny tables
__global__ __launch_bounds__(64) void k_tables(
    const float* __restrict__ e_emb1, const float* __restrict__ lew1,
    const float* __restrict__ ae1,
    const float* __restrict__ e_emb2, const float* __restrict__ lew2,
    const float* __restrict__ ae2,
    float* __restrict__ aet1, float* __restrict__ aet2)
{
    __shared__ float M1[16];
    __shared__ float M2[4];
    int t = threadIdx.x;
    if (t < 16) {
        int d = t >> 2, h = t & 3;
        float s = 0.f;
        for (int c = 0; c < 64; ++c) s += lew1[d * 256 + h * 64 + c] * ae1[h * 64 + c];
        M1[d * 4 + h] = s;
    }
    if (t < 4) {
        float s = 0.f;
        for (int c = 0; c < 64; ++c) s += lew2[t * 64 + c] * ae2[c];
        M2[t] = s;
    }
    __syncthreads();
    if (t < 16) {
        int ty = t >> 2, h = t & 3;
        float s = 0.f;
        for (int d = 0; d < 4; ++d) s += e_emb1[ty * 4 + d] * M1[d * 4 + h];
        aet1[ty * 4 + h] = s;
    }
    if (t < 4) {
        float s = 0.f;
        for (int d = 0; d < 4; ++d) s += e_emb2[t * 4 + d] * M2[d];
        aet2[t] = s;
    }
}

// ------------------------------------- FE stage 1: relu(X@W1+b1), bf16 MFMA
__global__ __launch_bounds__(256) void k_fe1(
    const float* __restrict__ feat, const float* __restrict__ w1,
    const float* __restrict__ b1, float* __restrict__ t1, int N)
{
    __shared__ __align__(16) unsigned short A_lds[8 * 64 * 8];  // 8 KiB
    __shared__ __align__(16) unsigned short B_lds[8 * 64 * 8];  // 8 KiB
    int t = threadIdx.x;
    int wv = t >> 6, lane = t & 63;
    int quad = lane >> 4, l16 = lane & 15;
    long n0 = (long)blockIdx.x * 64;

    floatx4 acc[4];
#pragma unroll
    for (int i = 0; i < 4; ++i) acc[i] = (floatx4){0.f, 0.f, 0.f, 0.f};

    int srow = t >> 2;
    int sf4 = t & 3;
    long arow = n0 + srow;
    if (arow >= N) arow = N - 1;
    const float* fbase = feat + arow * 768;

    for (int kc = 0; kc < 768; kc += 64) {
        __syncthreads();
#pragma unroll
        for (int i = 0; i < 4; ++i) {
            int f = sf4 + i * 4;
            int kl = f * 4;
            float4 v = *(const float4*)(fbase + kc + kl);
            int kg = kl >> 3, ko = kl & 7;
            unsigned short* d = &A_lds[(kg * 64 + srow) * 8 + ko];
            ushort4 pk = {f2bf(v.x), f2bf(v.y), f2bf(v.z), f2bf(v.w)};
            *(ushort4*)d = pk;
        }
#pragma unroll
        for (int i = 0; i < 4; ++i) {
            int f = sf4 + i * 4;
            int nl = f * 4;
            int kl = srow;
            float4 v = *(const float4*)(w1 + (long)(kc + kl) * 64 + nl);
            int kg = kl >> 3, j = kl & 7;
            B_lds[(kg * 64 + nl + 0) * 8 + j] = f2bf(v.x);
            B_lds[(kg * 64 + nl + 1) * 8 + j] = f2bf(v.y);
            B_lds[(kg * 64 + nl + 2) * 8 + j] = f2bf(v.z);
            B_lds[(kg * 64 + nl + 3) * 8 + j] = f2bf(v.w);
        }
        __syncthreads();
#pragma unroll
        for (int s = 0; s < 2; ++s) {
            int kg0 = s * 4 + quad;
            short8 bfrag = *(const short8*)&B_lds[(kg0 * 64 + wv * 16 + l16) * 8];
#pragma unroll
            for (int mt = 0; mt < 4; ++mt) {
                short8 afrag = *(const short8*)&A_lds[(kg0 * 64 + mt * 16 + l16) * 8];
                acc[mt] = __builtin_amdgcn_mfma_f32_16x16x32_bf16(
                    afrag, bfrag, acc[mt], 0, 0, 0);
            }
        }
    }
    int col = wv * 16 + l16;
    float bb = b1[col];
#pragma unroll
    for (int mt = 0; mt < 4; ++mt) {
#pragma unroll
        for (int r = 0; r < 4; ++r) {
            long m = n0 + mt * 16 + quad * 4 + r;
            if (m < N) t1[m * 64 + col] = fmaxf(acc[mt][r] + bb, 0.f);
        }
    }
}

// ------------------------- FE tail: (@W2+b2 + emb + pos terms) @ out_w + b
__global__ __launch_bounds__(256) void k_fe2(
    const float* __restrict__ t1, const float* __restrict__ w2,
    const float* __restrict__ b2, const int* __restrict__ ntypes,
    const float* __restrict__ temb, const float* __restrict__ pos,
    const float* __restrict__ posw, const float* __restrict__ posb,
    const float* __restrict__ outw, const float* __restrict__ outb,
    float* __restrict__ hfe)
{
    __shared__ float l1[256];
    __shared__ float l2[256];
    int t = threadIdx.x;
    long base = (long)blockIdx.x * 256;
    l1[t] = t1[base + t];
    __syncthreads();
    int r = t >> 6, c = t & 63;
    float acc = 0.f;
#pragma unroll 8
    for (int k = 0; k < 64; ++k) acc += l1[r * 64 + k] * w2[k * 64 + c];
    long n = (long)blockIdx.x * 4 + r;
    int nt = ntypes[n];
    acc += b2[c] + temb[nt * 64 + c] + pos[n] * posw[c] + posb[c];
    l2[r * 64 + c] = acc;
    __syncthreads();
    float acc2 = 0.f;
#pragma unroll 8
    for (int k = 0; k < 64; ++k) acc2 += l2[r * 64 + k] * outw[k * 64 + c];
    hfe[n * 64 + c] = acc2 + outb[c];
}

// ------------- layer-1 prep: xs1 = hfe@lin_w, res_pre1 = bias+hfe@res_w+res_b
__global__ __launch_bounds__(256) void k_prep1(
    const float* __restrict__ hfe, const float* __restrict__ lin_w,
    const float* __restrict__ res_w, const float* __restrict__ bias,
    const float* __restrict__ res_b, const float* __restrict__ att_s,
    const float* __restrict__ att_d, float* __restrict__ xs1,
    float* __restrict__ res_pre, float* __restrict__ a_src,
    float* __restrict__ a_dst)
{
    __shared__ float lh[512];
    int c = threadIdx.x;
    long n0 = (long)blockIdx.x * 8;
    for (int idx = c; idx < 512; idx += 256) lh[idx] = hfe[n0 * 64 + idx];
    __syncthreads();
    float ax[8], ar[8];
#pragma unroll
    for (int r = 0; r < 8; ++r) { ax[r] = 0.f; ar[r] = 0.f; }
    for (int k = 0; k < 64; ++k) {
        float wl = lin_w[k * 256 + c];
        float wr = res_w[k * 256 + c];
#pragma unroll
        for (int r = 0; r < 8; ++r) {
            float h = lh[r * 64 + k];
            ax[r] += h * wl;
            ar[r] += h * wr;
        }
    }
    float badd = bias[c] + res_b[c];
    float as = att_s[c], ad = att_d[c];
    int hh = c >> 6, lane = c & 63;
#pragma unroll
    for (int r = 0; r < 8; ++r) {
        long n = n0 + r;
        xs1[n * 256 + c] = ax[r];
        res_pre[n * 256 + c] = ar[r] + badd;
        float p = ax[r] * as, q = ax[r] * ad;
#pragma unroll
        for (int k2 = 32; k2; k2 >>= 1) {
            p += __shfl_xor(p, k2, 64);
            q += __shfl_xor(q, k2, 64);
        }
        if (lane == 0) { a_src[n * 4 + hh] = p; a_dst[n * 4 + hh] = q; }
    }
}

// ---------------------------------------------------------------- CSR build
__global__ __launch_bounds__(256) void k_count(
    const int* __restrict__ dst, const int* __restrict__ et,
    int* __restrict__ cnt_t, int E)
{
    int e = blockIdx.x * 256 + threadIdx.x;
    if (e < E) atomicAdd(&cnt_t[dst[e] * 4 + et[e]], 1);
}

__global__ __launch_bounds__(256) void k_scan1(
    const int* __restrict__ cnt_t, int* __restrict__ row_off,
    int* __restrict__ blk_sums, int N)
{
    __shared__ int s[256];
    int t = threadIdx.x;
    int i = blockIdx.x * 256 + t;
    int v = 0;
    if (i < N) v = cnt_t[4 * i] + cnt_t[4 * i + 1] + cnt_t[4 * i + 2] + cnt_t[4 * i + 3];
    s[t] = v;
    __syncthreads();
    for (int off = 1; off < 256; off <<= 1) {
        int x = 0;
        if (t >= off) x = s[t - off];
        __syncthreads();
        s[t] += x;
        __syncthreads();
    }
    if (i < N) row_off[i] = s[t] - v;
    if (t == 255) blk_sums[blockIdx.x] = s[255];
}

__global__ __launch_bounds__(256) void k_scan2(int* __restrict__ blk_sums, int nb)
{
    __shared__ int s[256];
    int t = threadIdx.x;
    int v = (t < nb) ? blk_sums[t] : 0;
    s[t] = v;
    __syncthreads();
    for (int off = 1; off < 256; off <<= 1) {
        int x = 0;
        if (t >= off) x = s[t - off];
        __syncthreads();
        s[t] += x;
        __syncthreads();
    }
    if (t < nb) blk_sums[t] = s[t] - v;
}

__global__ __launch_bounds__(256) void k_scan3(
    int* __restrict__ row_off, int* __restrict__ cursor,
    const int* __restrict__ blk_sums, int N, int E)
{
    int t = threadIdx.x;
    int i = blockIdx.x * 256 + t;
    if (i < N) {
        int o = row_off[i] + blk_sums[blockIdx.x];
        row_off[i] = o;
        cursor[i] = o;
    }
    if (i == 0) row_off[N] = E;
}

// scatter with (src | ty<<28) packing — N < 2^28, ty < 4
__global__ __launch_bounds__(256) void k_scatter(
    const int* __restrict__ src, const int* __restrict__ dst,
    const int* __restrict__ et, int* __restrict__ cursor,
    int* __restrict__ csr_pack, int E)
{
    int e = blockIdx.x * 256 + threadIdx.x;
    if (e < E) {
        int d = dst[e];
        int pos = atomicAdd(&cursor[d], 1);
        csr_pack[pos] = src[e] | (et[e] << 28);
    }
}

// --------------------------- GAT layer 1: fused softmax+agg+residual+LN+ReLU
// block = 256 = 4 waves; wave h = head h, lane = channel c.
// Chunked pass 2: lane-parallel alpha/exp (one edge per lane), packed (w,src)
// float2 in wave-private LDS, then broadcast-read aggregation, 4-way unrolled.
__global__ __launch_bounds__(256) void k_gat1(
    const float* __restrict__ xs1, const float* __restrict__ a_src,
    const float* __restrict__ a_dst, const int* __restrict__ row_off,
    const int* __restrict__ csr_pack,
    const int* __restrict__ cnt_t, const float* __restrict__ aet1,
    const float* __restrict__ ln_g, const float* __restrict__ ln_b,
    float* io)
{
    __shared__ __align__(8) float2 ws[4][64];
    __shared__ float red[8];
    int n = blockIdx.x;
    int t = threadIdx.x;
    int h = t >> 6, c = t & 63;
    int off = row_off[n], deg = row_off[n + 1] - off;
    float a_d = a_dst[n * 4 + h];
    float ael = 0.f;
    int degc = 0;
#pragma unroll
    for (int ty = 0; ty < 4; ++ty) {
        int ct = cnt_t[n * 4 + ty];
        degc += ct;
        ael += (float)ct * aet1[ty * 4 + h];
    }
    ael *= (degc > 0 ? 1.f / (float)degc : 1.f);
    float al = a_src[n * 4 + h] + a_d + ael;
    al = LRELU(al);
    // pass 1: max over in-edges (+ self loop), lane-strided
    float m = al;
    for (int i = c; i < deg; i += 64) {
        int pk = csr_pack[off + i];
        int s = pk & 0x0FFFFFFF, ty = ((unsigned)pk) >> 28;
        float a = a_src[s * 4 + h] + a_d + aet1[ty * 4 + h];
        a = LRELU(a);
        m = fmaxf(m, a);
    }
#pragma unroll
    for (int k = 32; k; k >>= 1) m = fmaxf(m, __shfl_xor(m, k, 64));
    // pass 2: chunked
    float wself = expf(al - m);
    float acc = wself * xs1[(long)n * 256 + h * 64 + c];
    float dpart = 0.f;
    const float* xb = xs1 + h * 64 + c;
    for (int base = 0; base < deg; base += 64) {
        int cnt = min(64, deg - base);
        float w = 0.f;
        int s = 0;
        if (c < cnt) {
            int pk = csr_pack[off + base + c];
            s = pk & 0x0FFFFFFF;
            int ty = ((unsigned)pk) >> 28;
            float a = a_src[s * 4 + h] + a_d + aet1[ty * 4 + h];
            a = LRELU(a);
            w = expf(a - m);
        }
        dpart += w;
        ws[h][c] = make_float2(w, __int_as_float(s));
        __syncthreads();
        int i = 0;
        float ac0 = 0.f, ac1 = 0.f, ac2 = 0.f, ac3 = 0.f;
        for (; i + 4 <= cnt; i += 4) {
            float2 p0 = ws[h][i + 0];
            float2 p1 = ws[h][i + 1];
            float2 p2 = ws[h][i + 2];
            float2 p3 = ws[h][i + 3];
            ac0 += p0.x * xb[(long)__float_as_int(p0.y) * 256];
            ac1 += p1.x * xb[(long)__float_as_int(p1.y) * 256];
            ac2 += p2.x * xb[(long)__float_as_int(p2.y) * 256];
            ac3 += p3.x * xb[(long)__float_as_int(p3.y) * 256];
        }
        for (; i < cnt; ++i) {
            float2 p = ws[h][i];
            ac0 += p.x * xb[(long)__float_as_int(p.y) * 256];
        }
        acc += (ac0 + ac1) + (ac2 + ac3);
        __syncthreads();  // before next chunk overwrites ws
    }
#pragma unroll
    for (int k = 32; k; k >>= 1) dpart += __shfl_xor(dpart, k, 64);
    float dsum = dpart + wself;
    float v = acc / (dsum + 1e-16f) + io[(long)n * 256 + t];
    // LayerNorm over 256 + ReLU
    float s1 = v, s2 = v * v;
#pragma unroll
    for (int k = 32; k; k >>= 1) {
        s1 += __shfl_xor(s1, k, 64);
        s2 += __shfl_xor(s2, k, 64);
    }
    if (c == 0) { red[h] = s1; red[4 + h] = s2; }
    __syncthreads();
    float tot1 = red[0] + red[1] + red[2] + red[3];
    float tot2 = red[4] + red[5] + red[6] + red[7];
    float mu = tot1 * (1.f / 256.f);
    float var = tot2 * (1.f / 256.f) - mu * mu;
    float y = (v - mu) * rsqrtf(var + 1e-5f) * ln_g[t] + ln_b[t];
    io[(long)n * 256 + t] = fmaxf(y, 0.f);
}

// ------------- layer-2 prep: xs2 = hid1@lin_w, res_pre2, a_src2/a_dst2 (H=1)
__global__ __launch_bounds__(256) void k_prep2(
    const float* __restrict__ hid1, const float* __restrict__ lin_w,
    const float* __restrict__ res_w, const float* __restrict__ bias,
    const float* __restrict__ res_b, const float* __restrict__ att_s,
    const float* __restrict__ att_d, float* __restrict__ xs2,
    float* __restrict__ res_pre, float* __restrict__ a_src,
    float* __restrict__ a_dst)
{
    __shared__ float lh[2048];
    int t = threadIdx.x;
    long n0 = (long)blockIdx.x * 8;
    for (int idx = t; idx < 2048; idx += 256) lh[idx] = hid1[n0 * 256 + idx];
    __syncthreads();
    int r = t >> 6, c = t & 63;
    float ax0 = 0.f, ar0 = 0.f, ax1 = 0.f, ar1 = 0.f;
    for (int k = 0; k < 256; ++k) {
        float wl = lin_w[k * 64 + c];
        float wr = res_w[k * 64 + c];
        float h0 = lh[r * 256 + k], h1 = lh[(r + 4) * 256 + k];
        ax0 += h0 * wl;
        ar0 += h0 * wr;
        ax1 += h1 * wl;
        ar1 += h1 * wr;
    }
    float badd = bias[c] + res_b[c];
    float as = att_s[c], ad = att_d[c];
    long na = n0 + r, nb2 = n0 + r + 4;
    xs2[na * 64 + c] = ax0;
    res_pre[na * 64 + c] = ar0 + badd;
    xs2[nb2 * 64 + c] = ax1;
    res_pre[nb2 * 64 + c] = ar1 + badd;
    float p0 = ax0 * as, q0 = ax0 * ad, p1 = ax1 * as, q1 = ax1 * ad;
#pragma unroll
    for (int k2 = 32; k2; k2 >>= 1) {
        p0 += __shfl_xor(p0, k2, 64);
        q0 += __shfl_xor(q0, k2, 64);
        p1 += __shfl_xor(p1, k2, 64);
        q1 += __shfl_xor(q1, k2, 64);
    }
    if (c == 0) { a_src[na] = p0; a_dst[na] = q0; a_src[nb2] = p1; a_dst[nb2] = q1; }
}

// --------------------------------- GAT layer 2 (H=1, C=64): one wave per node
__global__ __launch_bounds__(64) void k_gat2(
    const float* __restrict__ xs2, const float* __restrict__ a_src,
    const float* __restrict__ a_dst, const int* __restrict__ row_off,
    const int* __restrict__ csr_pack,
    const int* __restrict__ cnt_t, const float* __restrict__ aet2,
    const float* __restrict__ ln_g, const float* __restrict__ ln_b,
    float* io)
{
    __shared__ __align__(8) float2 ws[64];
    int n = blockIdx.x;
    int c = threadIdx.x;
    int off = row_off[n], deg = row_off[n + 1] - off;
    float a_d = a_dst[n];
    float ael = 0.f;
    int degc = 0;
#pragma unroll
    for (int ty = 0; ty < 4; ++ty) {
        int ct = cnt_t[n * 4 + ty];
        degc += ct;
        ael += (float)ct * aet2[ty];
    }
    ael *= (degc > 0 ? 1.f / (float)degc : 1.f);
    float al = a_src[n] + a_d + ael;
    al = LRELU(al);
    float m = al;
    for (int i = c; i < deg; i += 64) {
        int pk = csr_pack[off + i];
        int s = pk & 0x0FFFFFFF, ty = ((unsigned)pk) >> 28;
        float a = a_src[s] + a_d + aet2[ty];
        a = LRELU(a);
        m = fmaxf(m, a);
    }
#pragma unroll
    for (int k = 32; k; k >>= 1) m = fmaxf(m, __shfl_xor(m, k, 64));
    float wself = expf(al - m);
    float acc = wself * xs2[(long)n * 64 + c];
    float dpart = 0.f;
    const float* xb = xs2 + c;
    for (int base = 0; base < deg; base += 64) {
        int cnt = min(64, deg - base);
        float w = 0.f;
        int s = 0;
        if (c < cnt) {
            int pk = csr_pack[off + base + c];
            s = pk & 0x0FFFFFFF;
            int ty = ((unsigned)pk) >> 28;
            float a = a_src[s] + a_d + aet2[ty];
            a = LRELU(a);
            w = expf(a - m);
        }
        dpart += w;
        ws[c] = make_float2(w, __int_as_float(s));
        __syncthreads();
        int i = 0;
        float ac0 = 0.f, ac1 = 0.f, ac2 = 0.f, ac3 = 0.f;
        for (; i + 4 <= cnt; i += 4) {
            float2 p0 = ws[i + 0];
            float2 p1 = ws[i + 1];
            float2 p2 = ws[i + 2];
            float2 p3 = ws[i + 3];
            ac0 += p0.x * xb[(long)__float_as_int(p0.y) * 64];
            ac1 += p1.x * xb[(long)__float_as_int(p1.y) * 64];
            ac2 += p2.x * xb[(long)__float_as_int(p2.y) * 64];
            ac3 += p3.x * xb[(long)__float_as_int(p3.y) * 64];
        }
        for (; i < cnt; ++i) {
            float2 p = ws[i];
            ac0 += p.x * xb[(long)__float_as_int(p.y) * 64];
        }
        acc += (ac0 + ac1) + (ac2 + ac3);
        __syncthreads();
    }
#pragma unroll
    for (int k = 32; k; k >>= 1) dpart += __shfl_xor(dpart, k, 64);
    float dsum = dpart + wself;
    float v = acc / (dsum + 1e-16f) + io[(long)n * 64 + c];
    float s1 = v, s2 = v * v;
#pragma unroll
    for (int k = 32; k; k >>= 1) {
        s1 += __shfl_xor(s1, k, 64);
        s2 += __shfl_xor(s2, k, 64);
    }
    float mu = s1 * (1.f / 64.f);
    float var = s2 * (1.f / 64.f) - mu * mu;
    io[(long)n * 64 + c] = (v - mu) * rsqrtf(var + 1e-5f) * ln_g[c] + ln_b[c];
}

// --------------------------------------------------------------- classifier
__global__ __launch_bounds__(256) void k_cls(
    const float* __restrict__ hid2, const int* __restrict__ asp,
    const float* __restrict__ w, const float* __restrict__ b,
    float* __restrict__ out)
{
    int g = blockIdx.x * 256 + threadIdx.x;
    int i = g / 3, j = g - i * 3;
    int a = asp[i];
    float acc = b[j];
#pragma unroll 8
    for (int cc = 0; cc < 64; ++cc) acc += hid2[(long)a * 64 + cc] * w[cc * 3 + j];
    out[i * 3 + j] = acc;
}

extern "C" void kernel_launch(void* const* d_in, const int* in_sizes, int n_in,
                              void* d_out, int out_size, void* d_ws, size_t ws_size,
                              hipStream_t stream)
{
    const float* features    = (const float*)d_in[0];
    const int*   edge_index  = (const int*)d_in[1];
    const int*   aspect      = (const int*)d_in[2];
    const int*   etypes      = (const int*)d_in[3];
    const int*   ntypes      = (const int*)d_in[4];
    const float* pos         = (const float*)d_in[5];
    const float* fe_w1       = (const float*)d_in[6];
    const float* fe_b1       = (const float*)d_in[7];
    const float* fe_w2       = (const float*)d_in[8];
    const float* fe_b2       = (const float*)d_in[9];
    const float* fe_pos_w    = (const float*)d_in[10];
    const float* fe_pos_b    = (const float*)d_in[11];
    const float* fe_type_emb = (const float*)d_in[12];
    const float* fe_out_w    = (const float*)d_in[13];
    const float* fe_out_b    = (const float*)d_in[14];
    const float* g1_lin_w    = (const float*)d_in[15];
    const float* g1_att_src  = (const float*)d_in[16];
    const float* g1_att_dst  = (const float*)d_in[17];
    const float* g1_edge_emb = (const float*)d_in[18];
    const float* g1_lin_edge = (const float*)d_in[19];
    const float* g1_att_edge = (const float*)d_in[20];
    const float* g1_bias     = (const float*)d_in[21];
    const float* g1_res_w    = (const float*)d_in[22];
    const float* g1_res_b    = (const float*)d_in[23];
    const float* g1_ln_g     = (const float*)d_in[24];
    const float* g1_ln_b     = (const float*)d_in[25];
    const float* g2_lin_w    = (const float*)d_in[26];
    const float* g2_att_src  = (const float*)d_in[27];
    const float* g2_att_dst  = (const float*)d_in[28];
    const float* g2_edge_emb = (const float*)d_in[29];
    const float* g2_lin_edge = (const float*)d_in[30];
    const float* g2_att_edge = (const float*)d_in[31];
    const float* g2_bias     = (const float*)d_in[32];
    const float* g2_res_w    = (const float*)d_in[33];
    const float* g2_res_b    = (const float*)d_in[34];
    const float* g2_ln_g     = (const float*)d_in[35];
    const float* g2_ln_b     = (const float*)d_in[36];
    const float* cls_w       = (const float*)d_in[37];
    const float* cls_b       = (const float*)d_in[38];

    const int N = in_sizes[0] / 768;   // 50000
    const int E = in_sizes[1] / 2;     // 800000
    const int* src = edge_index;
    const int* dst = edge_index + E;

    char* wsb = (char*)d_ws;
    size_t off = 0;
    auto alloc = [&](size_t bytes) -> char* {
        char* p = wsb + off;
        off += (bytes + 255) & ~(size_t)255;
        return p;
    };
    float* t1      = (float*)alloc((size_t)N * 64 * 4);   // FE stage-1; reused as xs2
    float* hfe     = (float*)alloc((size_t)N * 64 * 4);
    float* xs1     = (float*)alloc((size_t)N * 256 * 4);
    float* rp1     = (float*)alloc((size_t)N * 256 * 4);  // res_pre1, then hid1
    float* rp2     = (float*)alloc((size_t)N * 64 * 4);   // res_pre2, then hid2
    float* a_src1  = (float*)alloc((size_t)N * 4 * 4);
    float* a_dst1  = (float*)alloc((size_t)N * 4 * 4);
    float* a_src2  = (float*)alloc((size_t)N * 4);
    float* a_dst2  = (float*)alloc((size_t)N * 4);
    int*   cnt_t   = (int*)alloc((size_t)N * 4 * 4);
    int*   row_off = (int*)alloc((size_t)(N + 1) * 4);
    int*   cursor  = (int*)alloc((size_t)N * 4);
    int*   blk     = (int*)alloc(1024);
    int*   csr_pack= (int*)alloc((size_t)E * 4);
    float* aet1    = (float*)alloc(64);
    float* aet2    = (float*)alloc(64);
    float* xs2     = t1;

    hipMemsetAsync(cnt_t, 0, (size_t)N * 4 * 4, stream);

    k_tables<<<1, 64, 0, stream>>>(g1_edge_emb, g1_lin_edge, g1_att_edge,
                                   g2_edge_emb, g2_lin_edge, g2_att_edge, aet1, aet2);
    k_fe1<<<(N + 63) / 64, 256, 0, stream>>>(features, fe_w1, fe_b1, t1, N);
    k_fe2<<<N / 4, 256, 0, stream>>>(t1, fe_w2, fe_b2, ntypes, fe_type_emb, pos,
                                     fe_pos_w, fe_pos_b, fe_out_w, fe_out_b, hfe);
    k_prep1<<<N / 8, 256, 0, stream>>>(hfe, g1_lin_w, g1_res_w, g1_bias, g1_res_b,
                                       g1_att_src, g1_att_dst, xs1, rp1, a_src1, a_dst1);
    int eblk = (E + 255) / 256;
    int nb = (N + 255) / 256;
    k_count<<<eblk, 256, 0, stream>>>(dst, etypes, cnt_t, E);
    k_scan1<<<nb, 256, 0, stream>>>(cnt_t, row_off, blk, N);
    k_scan2<<<1, 256, 0, stream>>>(blk, nb);
    k_scan3<<<nb, 256, 0, stream>>>(row_off, cursor, blk, N, E);
    k_scatter<<<eblk, 256, 0, stream>>>(src, dst, etypes, cursor, csr_pack, E);
    k_gat1<<<N, 256, 0, stream>>>(xs1, a_src1, a_dst1, row_off, csr_pack,
                                  cnt_t, aet1, g1_ln_g, g1_ln_b, rp1);
    k_prep2<<<N / 8, 256, 0, stream>>>(rp1, g2_lin_w, g2_res_w, g2_bias, g2_res_b,
                                       g2_att_src, g2_att_dst, xs2, rp2, a_src2, a_dst2);
    k_gat2<<<N, 64, 0, stream>>>(xs2, a_src2, a_dst2, row_off, csr_pack,
                                 cnt_t, aet2, g2_ln_g, g2_ln_b, rp2);
    k_cls<<<(out_size + 255) / 256, 256, 0, stream>>>(rp2, aspect, cls_w, cls_b,
                                                      (float*)d_out);
}

// Round 5
// 792.205 us; speedup vs baseline: 1.4949x; 1.1014x over previous
//
#include <hip/hip_runtime.h>

// SimplifiedHAFE on MI355X — round 4: bf16 gathers + 2-wave gat1 + no max pass.
// Round-3 profile: k_gat1 169 us, VALU 63%, HBM 39%, FETCH 463 MB vs 800 MB
// logical gather floor (xs1 misses L2, L3-served). Changes:
//  (1) xs1/xs2 stored bf16 -> gather bytes halve;
//  (2) k_gat1 = 128 thr / 2 waves, wave w owns heads 2w,2w+1, lane owns a
//      bf16x2 channel pair -> 2 coalesced 256B loads per edge instead of 4,
//      wave-private LDS weights -> no __syncthreads in the edge loop;
//  (3) softmax max-pass dropped (alpha bounded ~|0.5|; exp(a)/sum identical).
// k_gat2 same treatment (H=1). prep1/prep2 emit bf16 xs.

#define LRELU(x) ((x) > 0.f ? (x) : 0.2f * (x))

typedef __attribute__((ext_vector_type(8))) short short8;
typedef __attribute__((ext_vector_type(4))) float floatx4;

__device__ __forceinline__ unsigned short f2bf(float x) {
    union { float f; unsigned int u; } v; v.f = x;
    unsigned int r = (v.u + 0x7FFFu + ((v.u >> 16) & 1u)) >> 16;  // RNE
    return (unsigned short)r;
}
__device__ __forceinline__ float bflo(unsigned int u) {
    return __uint_as_float(u << 16);
}
__device__ __forceinline__ float bfhi(unsigned int u) {
    return __uint_as_float(u & 0xFFFF0000u);
}

// ---------------------------------------------------------------- tiny tables
__global__ __launch_bounds__(64) void k_tables(
    const float* __restrict__ e_emb1, const float* __restrict__ lew1,
    const float* __restrict__ ae1,
    const float* __restrict__ e_emb2, const float* __restrict__ lew2,
    const float* __restrict__ ae2,
    float* __restrict__ aet1, float* __restrict__ aet2)
{
    __shared__ float M1[16];
    __shared__ float M2[4];
    int t = threadIdx.x;
    if (t < 16) {
        int d = t >> 2, h = t & 3;
        float s = 0.f;
        for (int c = 0; c < 64; ++c) s += lew1[d * 256 + h * 64 + c] * ae1[h * 64 + c];
        M1[d * 4 + h] = s;
    }
    if (t < 4) {
        float s = 0.f;
        for (int c = 0; c < 64; ++c) s += lew2[t * 64 + c] * ae2[c];
        M2[t] = s;
    }
    __syncthreads();
    if (t < 16) {
        int ty = t >> 2, h = t & 3;
        float s = 0.f;
        for (int d = 0; d < 4; ++d) s += e_emb1[ty * 4 + d] * M1[d * 4 + h];
        aet1[ty * 4 + h] = s;
    }
    if (t < 4) {
        float s = 0.f;
        for (int d = 0; d < 4; ++d) s += e_emb2[t * 4 + d] * M2[d];
        aet2[t] = s;
    }
}

// ------------------------------------- FE stage 1: relu(X@W1+b1), bf16 MFMA
__global__ __launch_bounds__(256) void k_fe1(
    const float* __restrict__ feat, const float* __restrict__ w1,
    const float* __restrict__ b1, float* __restrict__ t1, int N)
{
    __shared__ __align__(16) unsigned short A_lds[8 * 64 * 8];
    __shared__ __align__(16) unsigned short B_lds[8 * 64 * 8];
    int t = threadIdx.x;
    int wv = t >> 6, lane = t & 63;
    int quad = lane >> 4, l16 = lane & 15;
    long n0 = (long)blockIdx.x * 64;

    floatx4 acc[4];
#pragma unroll
    for (int i = 0; i < 4; ++i) acc[i] = (floatx4){0.f, 0.f, 0.f, 0.f};

    int srow = t >> 2;
    int sf4 = t & 3;
    long arow = n0 + srow;
    if (arow >= N) arow = N - 1;
    const float* fbase = feat + arow * 768;

    for (int kc = 0; kc < 768; kc += 64) {
        __syncthreads();
#pragma unroll
        for (int i = 0; i < 4; ++i) {
            int f = sf4 + i * 4;
            int kl = f * 4;
            float4 v = *(const float4*)(fbase + kc + kl);
            int kg = kl >> 3, ko = kl & 7;
            unsigned short* d = &A_lds[(kg * 64 + srow) * 8 + ko];
            ushort4 pk = {f2bf(v.x), f2bf(v.y), f2bf(v.z), f2bf(v.w)};
            *(ushort4*)d = pk;
        }
#pragma unroll
        for (int i = 0; i < 4; ++i) {
            int f = sf4 + i * 4;
            int nl = f * 4;
            int kl = srow;
            float4 v = *(const float4*)(w1 + (long)(kc + kl) * 64 + nl);
            int kg = kl >> 3, j = kl & 7;
            B_lds[(kg * 64 + nl + 0) * 8 + j] = f2bf(v.x);
            B_lds[(kg * 64 + nl + 1) * 8 + j] = f2bf(v.y);
            B_lds[(kg * 64 + nl + 2) * 8 + j] = f2bf(v.z);
            B_lds[(kg * 64 + nl + 3) * 8 + j] = f2bf(v.w);
        }
        __syncthreads();
#pragma unroll
        for (int s = 0; s < 2; ++s) {
            int kg0 = s * 4 + quad;
            short8 bfrag = *(const short8*)&B_lds[(kg0 * 64 + wv * 16 + l16) * 8];
#pragma unroll
            for (int mt = 0; mt < 4; ++mt) {
                short8 afrag = *(const short8*)&A_lds[(kg0 * 64 + mt * 16 + l16) * 8];
                acc[mt] = __builtin_amdgcn_mfma_f32_16x16x32_bf16(
                    afrag, bfrag, acc[mt], 0, 0, 0);
            }
        }
    }
    int col = wv * 16 + l16;
    float bb = b1[col];
#pragma unroll
    for (int mt = 0; mt < 4; ++mt) {
#pragma unroll
        for (int r = 0; r < 4; ++r) {
            long m = n0 + mt * 16 + quad * 4 + r;
            if (m < N) t1[m * 64 + col] = fmaxf(acc[mt][r] + bb, 0.f);
        }
    }
}

// ------------------------- FE tail: (@W2+b2 + emb + pos terms) @ out_w + b
__global__ __launch_bounds__(256) void k_fe2(
    const float* __restrict__ t1, const float* __restrict__ w2,
    const float* __restrict__ b2, const int* __restrict__ ntypes,
    const float* __restrict__ temb, const float* __restrict__ pos,
    const float* __restrict__ posw, const float* __restrict__ posb,
    const float* __restrict__ outw, const float* __restrict__ outb,
    float* __restrict__ hfe)
{
    __shared__ float l1[256];
    __shared__ float l2[256];
    int t = threadIdx.x;
    long base = (long)blockIdx.x * 256;
    l1[t] = t1[base + t];
    __syncthreads();
    int r = t >> 6, c = t & 63;
    float acc = 0.f;
#pragma unroll 8
    for (int k = 0; k < 64; ++k) acc += l1[r * 64 + k] * w2[k * 64 + c];
    long n = (long)blockIdx.x * 4 + r;
    int nt = ntypes[n];
    acc += b2[c] + temb[nt * 64 + c] + pos[n] * posw[c] + posb[c];
    l2[r * 64 + c] = acc;
    __syncthreads();
    float acc2 = 0.f;
#pragma unroll 8
    for (int k = 0; k < 64; ++k) acc2 += l2[r * 64 + k] * outw[k * 64 + c];
    hfe[n * 64 + c] = acc2 + outb[c];
}

// ------ layer-1 prep: xs1(bf16) = hfe@lin_w, res_pre1, a_src1/a_dst1 scalars
__global__ __launch_bounds__(256) void k_prep1(
    const float* __restrict__ hfe, const float* __restrict__ lin_w,
    const float* __restrict__ res_w, const float* __restrict__ bias,
    const float* __restrict__ res_b, const float* __restrict__ att_s,
    const float* __restrict__ att_d, unsigned short* __restrict__ xs1b,
    float* __restrict__ res_pre, float* __restrict__ a_src,
    float* __restrict__ a_dst)
{
    __shared__ float lh[512];
    int c = threadIdx.x;
    long n0 = (long)blockIdx.x * 8;
    for (int idx = c; idx < 512; idx += 256) lh[idx] = hfe[n0 * 64 + idx];
    __syncthreads();
    float ax[8], ar[8];
#pragma unroll
    for (int r = 0; r < 8; ++r) { ax[r] = 0.f; ar[r] = 0.f; }
    for (int k = 0; k < 64; ++k) {
        float wl = lin_w[k * 256 + c];
        float wr = res_w[k * 256 + c];
#pragma unroll
        for (int r = 0; r < 8; ++r) {
            float h = lh[r * 64 + k];
            ax[r] += h * wl;
            ar[r] += h * wr;
        }
    }
    float badd = bias[c] + res_b[c];
    float as = att_s[c], ad = att_d[c];
    int hh = c >> 6, lane = c & 63;
#pragma unroll
    for (int r = 0; r < 8; ++r) {
        long n = n0 + r;
        xs1b[n * 256 + c] = f2bf(ax[r]);
        res_pre[n * 256 + c] = ar[r] + badd;
        float p = ax[r] * as, q = ax[r] * ad;
#pragma unroll
        for (int k2 = 32; k2; k2 >>= 1) {
            p += __shfl_xor(p, k2, 64);
            q += __shfl_xor(q, k2, 64);
        }
        if (lane == 0) { a_src[n * 4 + hh] = p; a_dst[n * 4 + hh] = q; }
    }
}

// ---------------------------------------------------------------- CSR build
__global__ __launch_bounds__(256) void k_count(
    const int* __restrict__ dst, const int* __restrict__ et,
    int* __restrict__ cnt_t, int E)
{
    int e = blockIdx.x * 256 + threadIdx.x;
    if (e < E) atomicAdd(&cnt_t[dst[e] * 4 + et[e]], 1);
}

__global__ __launch_bounds__(256) void k_scan1(
    const int* __restrict__ cnt_t, int* __restrict__ row_off,
    int* __restrict__ blk_sums, int N)
{
    __shared__ int s[256];
    int t = threadIdx.x;
    int i = blockIdx.x * 256 + t;
    int v = 0;
    if (i < N) v = cnt_t[4 * i] + cnt_t[4 * i + 1] + cnt_t[4 * i + 2] + cnt_t[4 * i + 3];
    s[t] = v;
    __syncthreads();
    for (int off = 1; off < 256; off <<= 1) {
        int x = 0;
        if (t >= off) x = s[t - off];
        __syncthreads();
        s[t] += x;
        __syncthreads();
    }
    if (i < N) row_off[i] = s[t] - v;
    if (t == 255) blk_sums[blockIdx.x] = s[255];
}

__global__ __launch_bounds__(256) void k_scan2(int* __restrict__ blk_sums, int nb)
{
    __shared__ int s[256];
    int t = threadIdx.x;
    int v = (t < nb) ? blk_sums[t] : 0;
    s[t] = v;
    __syncthreads();
    for (int off = 1; off < 256; off <<= 1) {
        int x = 0;
        if (t >= off) x = s[t - off];
        __syncthreads();
        s[t] += x;
        __syncthreads();
    }
    if (t < nb) blk_sums[t] = s[t] - v;
}

__global__ __launch_bounds__(256) void k_scan3(
    int* __restrict__ row_off, int* __restrict__ cursor,
    const int* __restrict__ blk_sums, int N, int E)
{
    int t = threadIdx.x;
    int i = blockIdx.x * 256 + t;
    if (i < N) {
        int o = row_off[i] + blk_sums[blockIdx.x];
        row_off[i] = o;
        cursor[i] = o;
    }
    if (i == 0) row_off[N] = E;
}

__global__ __launch_bounds__(256) void k_scatter(
    const int* __restrict__ src, const int* __restrict__ dst,
    const int* __restrict__ et, int* __restrict__ cursor,
    int* __restrict__ csr_pack, int E)
{
    int e = blockIdx.x * 256 + threadIdx.x;
    if (e < E) {
        int d = dst[e];
        int pos = atomicAdd(&cursor[d], 1);
        csr_pack[pos] = src[e] | (et[e] << 28);
    }
}

// ---------------- GAT layer 1: 128 thr = 2 waves; wave w owns heads 2w,2w+1.
// Lane c owns channel pair (128w+2c, +1) as bf16x2. No barriers in edge loop.
__global__ __launch_bounds__(128) void k_gat1(
    const unsigned short* __restrict__ xs1b, const float* __restrict__ a_src,
    const float* __restrict__ a_dst, const int* __restrict__ row_off,
    const int* __restrict__ csr_pack,
    const int* __restrict__ cnt_t, const float* __restrict__ aet1,
    const float* __restrict__ ln_g, const float* __restrict__ ln_b,
    float* io)
{
    __shared__ __align__(16) float4 ws[2][64];
    __shared__ float2 aetp[2][4];
    __shared__ float red[4];
    int n = blockIdx.x;
    int t = threadIdx.x;
    int w = t >> 6, c = t & 63;
    int h0 = 2 * w;
    if (t < 8) {
        int w2 = t >> 2, ty = t & 3;
        aetp[w2][ty] = make_float2(aet1[ty * 4 + 2 * w2], aet1[ty * 4 + 2 * w2 + 1]);
    }
    int off = row_off[n], deg = row_off[n + 1] - off;
    float2 a_d = *(const float2*)&a_dst[n * 4 + h0];
    __syncthreads();  // aetp visible
    // self-loop alpha (mean-edge-attr term via per-type counts)
    float ael0 = 0.f, ael1 = 0.f;
    int degc = 0;
#pragma unroll
    for (int ty = 0; ty < 4; ++ty) {
        int ct = cnt_t[n * 4 + ty];
        degc += ct;
        float2 ae = aetp[w][ty];
        ael0 += (float)ct * ae.x;
        ael1 += (float)ct * ae.y;
    }
    float inv = (degc > 0) ? 1.f / (float)degc : 1.f;
    float2 a_s_self = *(const float2*)&a_src[n * 4 + h0];
    float al0 = a_s_self.x + a_d.x + ael0 * inv;
    float al1 = a_s_self.y + a_d.y + ael1 * inv;
    al0 = LRELU(al0); al1 = LRELU(al1);
    float wself0 = expf(al0), wself1 = expf(al1);
    // accumulators for channel pair
    int col = w * 128 + 2 * c;
    unsigned int uself = *(const unsigned int*)&xs1b[(long)n * 256 + col];
    float wself_l = (c < 32) ? wself0 : wself1;
    float acc0 = wself_l * bflo(uself);
    float acc1 = wself_l * bfhi(uself);
    float dp0 = 0.f, dp1 = 0.f;
    const unsigned short* xcol = xs1b + col;
    for (int base = 0; base < deg; base += 64) {
        int cnt = min(64, deg - base);
        if (c < cnt) {
            int pk = csr_pack[off + base + c];
            int s = pk & 0x0FFFFFFF;
            int ty = ((unsigned)pk) >> 28;
            float2 as2 = *(const float2*)&a_src[s * 4 + h0];
            float2 ae = aetp[w][ty];
            float a0 = as2.x + a_d.x + ae.x;
            float a1 = as2.y + a_d.y + ae.y;
            a0 = LRELU(a0); a1 = LRELU(a1);
            float w0 = expf(a0), w1 = expf(a1);
            dp0 += w0; dp1 += w1;
            ws[w][c] = make_float4(w0, w1, __int_as_float(s), 0.f);
        }
        // wave-private LDS: no barrier needed (same wave writes & reads)
        int i = 0;
        float b00 = 0.f, b01 = 0.f, b10 = 0.f, b11 = 0.f;
        for (; i + 2 <= cnt; i += 2) {
            float4 p0 = ws[w][i];
            float4 p1 = ws[w][i + 1];
            unsigned int u0 = *(const unsigned int*)&xcol[(long)__float_as_int(p0.z) * 256];
            unsigned int u1 = *(const unsigned int*)&xcol[(long)__float_as_int(p1.z) * 256];
            float w0 = (c < 32) ? p0.x : p0.y;
            float w1 = (c < 32) ? p1.x : p1.y;
            b00 += w0 * bflo(u0); b01 += w0 * bfhi(u0);
            b10 += w1 * bflo(u1); b11 += w1 * bfhi(u1);
        }
        if (i < cnt) {
            float4 p = ws[w][i];
            unsigned int u = *(const unsigned int*)&xcol[(long)__float_as_int(p.z) * 256];
            float w0 = (c < 32) ? p.x : p.y;
            b00 += w0 * bflo(u); b01 += w0 * bfhi(u);
        }
        acc0 += b00 + b10;
        acc1 += b01 + b11;
    }
#pragma unroll
    for (int k = 32; k; k >>= 1) {
        dp0 += __shfl_xor(dp0, k, 64);
        dp1 += __shfl_xor(dp1, k, 64);
    }
    float dsum = ((c < 32) ? dp0 + wself0 : dp1 + wself1) + 1e-16f;
    float2 res = *(const float2*)&io[(long)n * 256 + col];
    float v0 = acc0 / dsum + res.x;
    float v1 = acc1 / dsum + res.y;
    // LayerNorm over 256 + ReLU (2-wave reduce)
    float s1 = v0 + v1, s2 = v0 * v0 + v1 * v1;
#pragma unroll
    for (int k = 32; k; k >>= 1) {
        s1 += __shfl_xor(s1, k, 64);
        s2 += __shfl_xor(s2, k, 64);
    }
    if (c == 0) { red[w] = s1; red[2 + w] = s2; }
    __syncthreads();
    float mu = (red[0] + red[1]) * (1.f / 256.f);
    float var = (red[2] + red[3]) * (1.f / 256.f) - mu * mu;
    float rs = rsqrtf(var + 1e-5f);
    float2 g = *(const float2*)&ln_g[col];
    float2 bln = *(const float2*)&ln_b[col];
    float y0 = fmaxf((v0 - mu) * rs * g.x + bln.x, 0.f);
    float y1 = fmaxf((v1 - mu) * rs * g.y + bln.y, 0.f);
    *(float2*)&io[(long)n * 256 + col] = make_float2(y0, y1);
}

// ------ layer-2 prep: xs2(bf16) = hid1@lin_w, res_pre2, a_src2/a_dst2 (H=1)
__global__ __launch_bounds__(256) void k_prep2(
    const float* __restrict__ hid1, const float* __restrict__ lin_w,
    const float* __restrict__ res_w, const float* __restrict__ bias,
    const float* __restrict__ res_b, const float* __restrict__ att_s,
    const float* __restrict__ att_d, unsigned short* __restrict__ xs2b,
    float* __restrict__ res_pre, float* __restrict__ a_src,
    float* __restrict__ a_dst)
{
    __shared__ float lh[2048];
    int t = threadIdx.x;
    long n0 = (long)blockIdx.x * 8;
    for (int idx = t; idx < 2048; idx += 256) lh[idx] = hid1[n0 * 256 + idx];
    __syncthreads();
    int r = t >> 6, c = t & 63;
    float ax0 = 0.f, ar0 = 0.f, ax1 = 0.f, ar1 = 0.f;
    for (int k = 0; k < 256; ++k) {
        float wl = lin_w[k * 64 + c];
        float wr = res_w[k * 64 + c];
        float h0 = lh[r * 256 + k], h1 = lh[(r + 4) * 256 + k];
        ax0 += h0 * wl;
        ar0 += h0 * wr;
        ax1 += h1 * wl;
        ar1 += h1 * wr;
    }
    float badd = bias[c] + res_b[c];
    float as = att_s[c], ad = att_d[c];
    long na = n0 + r, nb2 = n0 + r + 4;
    xs2b[na * 64 + c] = f2bf(ax0);
    res_pre[na * 64 + c] = ar0 + badd;
    xs2b[nb2 * 64 + c] = f2bf(ax1);
    res_pre[nb2 * 64 + c] = ar1 + badd;
    float p0 = ax0 * as, q0 = ax0 * ad, p1 = ax1 * as, q1 = ax1 * ad;
#pragma unroll
    for (int k2 = 32; k2; k2 >>= 1) {
        p0 += __shfl_xor(p0, k2, 64);
        q0 += __shfl_xor(q0, k2, 64);
        p1 += __shfl_xor(p1, k2, 64);
        q1 += __shfl_xor(q1, k2, 64);
    }
    if (c == 0) { a_src[na] = p0; a_dst[na] = q0; a_src[nb2] = p1; a_dst[nb2] = q1; }
}

// --------------------------------- GAT layer 2 (H=1, C=64): one wave per node
__global__ __launch_bounds__(64) void k_gat2(
    const unsigned short* __restrict__ xs2b, const float* __restrict__ a_src,
    const float* __restrict__ a_dst, const int* __restrict__ row_off,
    const int* __restrict__ csr_pack,
    const int* __restrict__ cnt_t, const float* __restrict__ aet2,
    const float* __restrict__ ln_g, const float* __restrict__ ln_b,
    float* io)
{
    __shared__ __align__(8) float2 ws[64];
    __shared__ float aetl[4];
    int n = blockIdx.x;
    int c = threadIdx.x;
    if (c < 4) aetl[c] = aet2[c];
    int off = row_off[n], deg = row_off[n + 1] - off;
    float a_d = a_dst[n];
    float ael = 0.f;
    int degc = 0;
#pragma unroll
    for (int ty = 0; ty < 4; ++ty) {
        int ct = cnt_t[n * 4 + ty];
        degc += ct;
        ael += (float)ct * aet2[ty];
    }
    ael *= (degc > 0 ? 1.f / (float)degc : 1.f);
    float al = a_src[n] + a_d + ael;
    al = LRELU(al);
    float wself = expf(al);
    float acc = wself * bflo((unsigned int)xs2b[(long)n * 64 + c] << 16 >> 16 | ((unsigned int)xs2b[(long)n * 64 + c] << 16));
    // simpler: recompute cleanly below
    acc = wself * __uint_as_float(((unsigned int)xs2b[(long)n * 64 + c]) << 16);
    float dp = 0.f;
    const unsigned short* xcol = xs2b + c;
    for (int base = 0; base < deg; base += 64) {
        int cnt = min(64, deg - base);
        if (c < cnt) {
            int pk = csr_pack[off + base + c];
            int s = pk & 0x0FFFFFFF;
            int ty = ((unsigned)pk) >> 28;
            float a = a_src[s] + a_d + aetl[ty];
            a = LRELU(a);
            float we = expf(a);
            dp += we;
            ws[c] = make_float2(we, __int_as_float(s));
        }
        int i = 0;
        float b0 = 0.f, b1 = 0.f;
        for (; i + 2 <= cnt; i += 2) {
            float2 p0 = ws[i];
            float2 p1 = ws[i + 1];
            unsigned int u0 = xcol[(long)__float_as_int(p0.y) * 64];
            unsigned int u1 = xcol[(long)__float_as_int(p1.y) * 64];
            b0 += p0.x * __uint_as_float(u0 << 16);
            b1 += p1.x * __uint_as_float(u1 << 16);
        }
        if (i < cnt) {
            float2 p = ws[i];
            unsigned int u = xcol[(long)__float_as_int(p.y) * 64];
            b0 += p.x * __uint_as_float(u << 16);
        }
        acc += b0 + b1;
    }
#pragma unroll
    for (int k = 32; k; k >>= 1) dp += __shfl_xor(dp, k, 64);
    float dsum = dp + wself + 1e-16f;
    float v = acc / dsum + io[(long)n * 64 + c];
    float s1 = v, s2 = v * v;
#pragma unroll
    for (int k = 32; k; k >>= 1) {
        s1 += __shfl_xor(s1, k, 64);
        s2 += __shfl_xor(s2, k, 64);
    }
    float mu = s1 * (1.f / 64.f);
    float var = s2 * (1.f / 64.f) - mu * mu;
    io[(long)n * 64 + c] = (v - mu) * rsqrtf(var + 1e-5f) * ln_g[c] + ln_b[c];
}

// --------------------------------------------------------------- classifier
__global__ __launch_bounds__(256) void k_cls(
    const float* __restrict__ hid2, const int* __restrict__ asp,
    const float* __restrict__ w, const float* __restrict__ b,
    float* __restrict__ out)
{
    int g = blockIdx.x * 256 + threadIdx.x;
    int i = g / 3, j = g - i * 3;
    int a = asp[i];
    float acc = b[j];
#pragma unroll 8
    for (int cc = 0; cc < 64; ++cc) acc += hid2[(long)a * 64 + cc] * w[cc * 3 + j];
    out[i * 3 + j] = acc;
}

extern "C" void kernel_launch(void* const* d_in, const int* in_sizes, int n_in,
                              void* d_out, int out_size, void* d_ws, size_t ws_size,
                              hipStream_t stream)
{
    const float* features    = (const float*)d_in[0];
    const int*   edge_index  = (const int*)d_in[1];
    const int*   aspect      = (const int*)d_in[2];
    const int*   etypes      = (const int*)d_in[3];
    const int*   ntypes      = (const int*)d_in[4];
    const float* pos         = (const float*)d_in[5];
    const float* fe_w1       = (const float*)d_in[6];
    const float* fe_b1       = (const float*)d_in[7];
    const float* fe_w2       = (const float*)d_in[8];
    const float* fe_b2       = (const float*)d_in[9];
    const float* fe_pos_w    = (const float*)d_in[10];
    const float* fe_pos_b    = (const float*)d_in[11];
    const float* fe_type_emb = (const float*)d_in[12];
    const float* fe_out_w    = (const float*)d_in[13];
    const float* fe_out_b    = (const float*)d_in[14];
    const float* g1_lin_w    = (const float*)d_in[15];
    const float* g1_att_src  = (const float*)d_in[16];
    const float* g1_att_dst  = (const float*)d_in[17];
    const float* g1_edge_emb = (const float*)d_in[18];
    const float* g1_lin_edge = (const float*)d_in[19];
    const float* g1_att_edge = (const float*)d_in[20];
    const float* g1_bias     = (const float*)d_in[21];
    const float* g1_res_w    = (const float*)d_in[22];
    const float* g1_res_b    = (const float*)d_in[23];
    const float* g1_ln_g     = (const float*)d_in[24];
    const float* g1_ln_b     = (const float*)d_in[25];
    const float* g2_lin_w    = (const float*)d_in[26];
    const float* g2_att_src  = (const float*)d_in[27];
    const float* g2_att_dst  = (const float*)d_in[28];
    const float* g2_edge_emb = (const float*)d_in[29];
    const float* g2_lin_edge = (const float*)d_in[30];
    const float* g2_att_edge = (const float*)d_in[31];
    const float* g2_bias     = (const float*)d_in[32];
    const float* g2_res_w    = (const float*)d_in[33];
    const float* g2_res_b    = (const float*)d_in[34];
    const float* g2_ln_g     = (const float*)d_in[35];
    const float* g2_ln_b     = (const float*)d_in[36];
    const float* cls_w       = (const float*)d_in[37];
    const float* cls_b       = (const float*)d_in[38];

    const int N = in_sizes[0] / 768;   // 50000
    const int E = in_sizes[1] / 2;     // 800000
    const int* src = edge_index;
    const int* dst = edge_index + E;

    char* wsb = (char*)d_ws;
    size_t off = 0;
    auto alloc = [&](size_t bytes) -> char* {
        char* p = wsb + off;
        off += (bytes + 255) & ~(size_t)255;
        return p;
    };
    float* t1      = (float*)alloc((size_t)N * 64 * 4);
    float* hfe     = (float*)alloc((size_t)N * 64 * 4);
    unsigned short* xs1b = (unsigned short*)alloc((size_t)N * 256 * 2);
    unsigned short* xs2b = (unsigned short*)alloc((size_t)N * 64 * 2);
    float* rp1     = (float*)alloc((size_t)N * 256 * 4);  // res_pre1, then hid1
    float* rp2     = (float*)alloc((size_t)N * 64 * 4);   // res_pre2, then hid2
    float* a_src1  = (float*)alloc((size_t)N * 4 * 4);
    float* a_dst1  = (float*)alloc((size_t)N * 4 * 4);
    float* a_src2  = (float*)alloc((size_t)N * 4);
    float* a_dst2  = (float*)alloc((size_t)N * 4);
    int*   cnt_t   = (int*)alloc((size_t)N * 4 * 4);
    int*   row_off = (int*)alloc((size_t)(N + 1) * 4);
    int*   cursor  = (int*)alloc((size_t)N * 4);
    int*   blk     = (int*)alloc(1024);
    int*   csr_pack= (int*)alloc((size_t)E * 4);
    float* aet1    = (float*)alloc(64);
    float* aet2    = (float*)alloc(64);

    hipMemsetAsync(cnt_t, 0, (size_t)N * 4 * 4, stream);

    k_tables<<<1, 64, 0, stream>>>(g1_edge_emb, g1_lin_edge, g1_att_edge,
                                   g2_edge_emb, g2_lin_edge, g2_att_edge, aet1, aet2);
    k_fe1<<<(N + 63) / 64, 256, 0, stream>>>(features, fe_w1, fe_b1, t1, N);
    k_fe2<<<N / 4, 256, 0, stream>>>(t1, fe_w2, fe_b2, ntypes, fe_type_emb, pos,
                                     fe_pos_w, fe_pos_b, fe_out_w, fe_out_b, hfe);
    k_prep1<<<N / 8, 256, 0, stream>>>(hfe, g1_lin_w, g1_res_w, g1_bias, g1_res_b,
                                       g1_att_src, g1_att_dst, xs1b, rp1, a_src1, a_dst1);
    int eblk = (E + 255) / 256;
    int nb = (N + 255) / 256;
    k_count<<<eblk, 256, 0, stream>>>(dst, etypes, cnt_t, E);
    k_scan1<<<nb, 256, 0, stream>>>(cnt_t, row_off, blk, N);
    k_scan2<<<1, 256, 0, stream>>>(blk, nb);
    k_scan3<<<nb, 256, 0, stream>>>(row_off, cursor, blk, N, E);
    k_scatter<<<eblk, 256, 0, stream>>>(src, dst, etypes, cursor, csr_pack, E);
    k_gat1<<<N, 128, 0, stream>>>(xs1b, a_src1, a_dst1, row_off, csr_pack,
                                  cnt_t, aet1, g1_ln_g, g1_ln_b, rp1);
    k_prep2<<<N / 8, 256, 0, stream>>>(rp1, g2_lin_w, g2_res_w, g2_bias, g2_res_b,
                                       g2_att_src, g2_att_dst, xs2b, rp2, a_src2, a_dst2);
    k_gat2<<<N, 64, 0, stream>>>(xs2b, a_src2, a_dst2, row_off, csr_pack,
                                 cnt_t, aet2, g2_ln_g, g2_ln_b, rp2);
    k_cls<<<(out_size + 255) / 256, 256, 0, stream>>>(rp2, aspect, cls_w, cls_b,
                                                      (float*)d_out);
}

// Round 6
// 699.331 us; speedup vs baseline: 1.6934x; 1.1328x over previous
//
#include <hip/hip_runtime.h>

// SimplifiedHAFE on MI355X — round 5: prep1/prep2 -> bf16 MFMA GEMM.
// Round-4 profile: k_prep2 = 119 us (VALU 40%, HBM 4.8%, Mfma 0) — issue-bound
// scalar matmul, 3.28 GF running 10x over its MFMA time; k_prep1 identical
// structure (hidden #2). New: templated k_prep_gemm<K,NH> (fe1 structure,
// 64x128 tile, frag-order LDS, fused f2bf staging) computing [lin_w|res_w]
// concat; epilogue writes xs bf16 + res_pre fp32 (+bias+res_b). Attention
// scalars a_src/a_dst via tiny k_att<H> reduce over bf16 xs.
// gat1/gat2 unchanged from round 4 (chunked lane-parallel, no max pass).

#define LRELU(x) ((x) > 0.f ? (x) : 0.2f * (x))

typedef __attribute__((ext_vector_type(8))) short short8;
typedef __attribute__((ext_vector_type(4))) float floatx4;

__device__ __forceinline__ unsigned short f2bf(float x) {
    union { float f; unsigned int u; } v; v.f = x;
    unsigned int r = (v.u + 0x7FFFu + ((v.u >> 16) & 1u)) >> 16;  // RNE
    return (unsigned short)r;
}
__device__ __forceinline__ float bflo(unsigned int u) {
    return __uint_as_float(u << 16);
}
__device__ __forceinline__ float bfhi(unsigned int u) {
    return __uint_as_float(u & 0xFFFF0000u);
}
__device__ __forceinline__ float bf1(unsigned short u) {
    return __uint_as_float(((unsigned int)u) << 16);
}

// ---------------------------------------------------------------- tiny tables
__global__ __launch_bounds__(64) void k_tables(
    const float* __restrict__ e_emb1, const float* __restrict__ lew1,
    const float* __restrict__ ae1,
    const float* __restrict__ e_emb2, const float* __restrict__ lew2,
    const float* __restrict__ ae2,
    float* __restrict__ aet1, float* __restrict__ aet2)
{
    __shared__ float M1[16];
    __shared__ float M2[4];
    int t = threadIdx.x;
    if (t < 16) {
        int d = t >> 2, h = t & 3;
        float s = 0.f;
        for (int c = 0; c < 64; ++c) s += lew1[d * 256 + h * 64 + c] * ae1[h * 64 + c];
        M1[d * 4 + h] = s;
    }
    if (t < 4) {
        float s = 0.f;
        for (int c = 0; c < 64; ++c) s += lew2[t * 64 + c] * ae2[c];
        M2[t] = s;
    }
    __syncthreads();
    if (t < 16) {
        int ty = t >> 2, h = t & 3;
        float s = 0.f;
        for (int d = 0; d < 4; ++d) s += e_emb1[ty * 4 + d] * M1[d * 4 + h];
        aet1[ty * 4 + h] = s;
    }
    if (t < 4) {
        float s = 0.f;
        for (int d = 0; d < 4; ++d) s += e_emb2[t * 4 + d] * M2[d];
        aet2[t] = s;
    }
}

// ------------------------------------- FE stage 1: relu(X@W1+b1), bf16 MFMA
__global__ __launch_bounds__(256) void k_fe1(
    const float* __restrict__ feat, const float* __restrict__ w1,
    const float* __restrict__ b1, float* __restrict__ t1, int N)
{
    __shared__ __align__(16) unsigned short A_lds[8 * 64 * 8];
    __shared__ __align__(16) unsigned short B_lds[8 * 64 * 8];
    int t = threadIdx.x;
    int wv = t >> 6, lane = t & 63;
    int quad = lane >> 4, l16 = lane & 15;
    long n0 = (long)blockIdx.x * 64;

    floatx4 acc[4];
#pragma unroll
    for (int i = 0; i < 4; ++i) acc[i] = (floatx4){0.f, 0.f, 0.f, 0.f};

    int srow = t >> 2;
    int sf4 = t & 3;
    long arow = n0 + srow;
    if (arow >= N) arow = N - 1;
    const float* fbase = feat + arow * 768;

    for (int kc = 0; kc < 768; kc += 64) {
        __syncthreads();
#pragma unroll
        for (int i = 0; i < 4; ++i) {
            int f = sf4 + i * 4;
            int kl = f * 4;
            float4 v = *(const float4*)(fbase + kc + kl);
            int kg = kl >> 3, ko = kl & 7;
            unsigned short* d = &A_lds[(kg * 64 + srow) * 8 + ko];
            ushort4 pk = {f2bf(v.x), f2bf(v.y), f2bf(v.z), f2bf(v.w)};
            *(ushort4*)d = pk;
        }
#pragma unroll
        for (int i = 0; i < 4; ++i) {
            int f = sf4 + i * 4;
            int nl = f * 4;
            int kl = srow;
            float4 v = *(const float4*)(w1 + (long)(kc + kl) * 64 + nl);
            int kg = kl >> 3, j = kl & 7;
            B_lds[(kg * 64 + nl + 0) * 8 + j] = f2bf(v.x);
            B_lds[(kg * 64 + nl + 1) * 8 + j] = f2bf(v.y);
            B_lds[(kg * 64 + nl + 2) * 8 + j] = f2bf(v.z);
            B_lds[(kg * 64 + nl + 3) * 8 + j] = f2bf(v.w);
        }
        __syncthreads();
#pragma unroll
        for (int s = 0; s < 2; ++s) {
            int kg0 = s * 4 + quad;
            short8 bfrag = *(const short8*)&B_lds[(kg0 * 64 + wv * 16 + l16) * 8];
#pragma unroll
            for (int mt = 0; mt < 4; ++mt) {
                short8 afrag = *(const short8*)&A_lds[(kg0 * 64 + mt * 16 + l16) * 8];
                acc[mt] = __builtin_amdgcn_mfma_f32_16x16x32_bf16(
                    afrag, bfrag, acc[mt], 0, 0, 0);
            }
        }
    }
    int col = wv * 16 + l16;
    float bb = b1[col];
#pragma unroll
    for (int mt = 0; mt < 4; ++mt) {
#pragma unroll
        for (int r = 0; r < 4; ++r) {
            long m = n0 + mt * 16 + quad * 4 + r;
            if (m < N) t1[m * 64 + col] = fmaxf(acc[mt][r] + bb, 0.f);
        }
    }
}

// ------------------------- FE tail: (@W2+b2 + emb + pos terms) @ out_w + b
__global__ __launch_bounds__(256) void k_fe2(
    const float* __restrict__ t1, const float* __restrict__ w2,
    const float* __restrict__ b2, const int* __restrict__ ntypes,
    const float* __restrict__ temb, const float* __restrict__ pos,
    const float* __restrict__ posw, const float* __restrict__ posb,
    const float* __restrict__ outw, const float* __restrict__ outb,
    float* __restrict__ hfe)
{
    __shared__ float l1[256];
    __shared__ float l2[256];
    int t = threadIdx.x;
    long base = (long)blockIdx.x * 256;
    l1[t] = t1[base + t];
    __syncthreads();
    int r = t >> 6, c = t & 63;
    float acc = 0.f;
#pragma unroll 8
    for (int k = 0; k < 64; ++k) acc += l1[r * 64 + k] * w2[k * 64 + c];
    long n = (long)blockIdx.x * 4 + r;
    int nt = ntypes[n];
    acc += b2[c] + temb[nt * 64 + c] + pos[n] * posw[c] + posb[c];
    l2[r * 64 + c] = acc;
    __syncthreads();
    float acc2 = 0.f;
#pragma unroll 8
    for (int k = 0; k < 64; ++k) acc2 += l2[r * 64 + k] * outw[k * 64 + c];
    hfe[n * 64 + c] = acc2 + outb[c];
}

// ---------------- prep GEMM: A[NxK] @ [B1|B2][Kx2NH] -> xs bf16 + res fp32
// Block 256 thr = 4 waves; tile M=64 x 128 cols; wave owns 32 cols (2 tiles).
// grid.y = col-tile over 2NH in 128-col chunks.
template<int K, int NH>
__global__ __launch_bounds__(256) void k_prep_gemm(
    const float* __restrict__ A, const float* __restrict__ B1,
    const float* __restrict__ B2, const float* __restrict__ bias,
    const float* __restrict__ res_b, unsigned short* __restrict__ xsb,
    float* __restrict__ resp, int N)
{
    __shared__ __align__(16) unsigned short A_lds[8 * 64 * 8];    // 8 KB
    __shared__ __align__(16) unsigned short B_lds[8 * 128 * 8];   // 16 KB
    int t = threadIdx.x;
    int wv = t >> 6, lane = t & 63;
    int quad = lane >> 4, l16 = lane & 15;
    long n0 = (long)blockIdx.x * 64;
    int gcol0 = blockIdx.y * 128;

    floatx4 acc[4][2];
#pragma unroll
    for (int i = 0; i < 4; ++i)
#pragma unroll
        for (int j = 0; j < 2; ++j) acc[i][j] = (floatx4){0.f, 0.f, 0.f, 0.f};

    int srow = t >> 2, sf4 = t & 3;
    long arow = n0 + srow;
    if (arow >= N) arow = N - 1;
    const float* abase = A + arow * (long)K;
    int bk0 = t >> 5;   // 0..7
    int bc4 = t & 31;   // float4 col group

    for (int kc = 0; kc < K; kc += 64) {
        __syncthreads();
        // stage A (64 rows x 64 k): K/64 float4 per thread-row
#pragma unroll
        for (int i = 0; i < 4; ++i) {
            int f = sf4 + i * 4;
            int kl = f * 4;
            float4 v = *(const float4*)(abase + kc + kl);
            int kg = kl >> 3, ko = kl & 7;
            ushort4 pk = {f2bf(v.x), f2bf(v.y), f2bf(v.z), f2bf(v.w)};
            *(ushort4*)&A_lds[(kg * 64 + srow) * 8 + ko] = pk;
        }
        // stage B (64 k x 128 cols) from concat [B1|B2]
#pragma unroll
        for (int i = 0; i < 8; ++i) {
            int kl = bk0 + i * 8;
            int col4 = bc4 * 4;
            int gc = gcol0 + col4;
            const float* bsrc = (gc < NH) ? (B1 + (long)(kc + kl) * NH + gc)
                                          : (B2 + (long)(kc + kl) * NH + gc - NH);
            float4 v = *(const float4*)bsrc;
            int kg = kl >> 3, j = kl & 7;
            B_lds[(kg * 128 + col4 + 0) * 8 + j] = f2bf(v.x);
            B_lds[(kg * 128 + col4 + 1) * 8 + j] = f2bf(v.y);
            B_lds[(kg * 128 + col4 + 2) * 8 + j] = f2bf(v.z);
            B_lds[(kg * 128 + col4 + 3) * 8 + j] = f2bf(v.w);
        }
        __syncthreads();
#pragma unroll
        for (int s = 0; s < 2; ++s) {
            int kg0 = s * 4 + quad;
#pragma unroll
            for (int nt = 0; nt < 2; ++nt) {
                short8 bfrag = *(const short8*)&B_lds[(kg0 * 128 + wv * 32 + nt * 16 + l16) * 8];
#pragma unroll
                for (int mt = 0; mt < 4; ++mt) {
                    short8 afrag = *(const short8*)&A_lds[(kg0 * 64 + mt * 16 + l16) * 8];
                    acc[mt][nt] = __builtin_amdgcn_mfma_f32_16x16x32_bf16(
                        afrag, bfrag, acc[mt][nt], 0, 0, 0);
                }
            }
        }
    }
    // epilogue: cols < NH -> xs bf16; cols >= NH -> res fp32 (+bias+res_b)
#pragma unroll
    for (int nt = 0; nt < 2; ++nt) {
        int gc = gcol0 + wv * 32 + nt * 16 + l16;
        bool isl = gc < NH;
        int oc = isl ? gc : gc - NH;
        float badd = isl ? 0.f : (bias[oc] + res_b[oc]);
#pragma unroll
        for (int mt = 0; mt < 4; ++mt) {
#pragma unroll
            for (int r = 0; r < 4; ++r) {
                long m = n0 + mt * 16 + quad * 4 + r;
                if (m < N) {
                    float val = acc[mt][nt][r];
                    if (isl) xsb[m * NH + oc] = f2bf(val);
                    else     resp[m * NH + oc] = val + badd;
                }
            }
        }
    }
}

// --------- attention scalars: a_src/a_dst[n,h] = dot(xs[n,h*64:+64], att)
template<int H>
__global__ __launch_bounds__(256) void k_att(
    const unsigned short* __restrict__ xsb, const float* __restrict__ att_s,
    const float* __restrict__ att_d, float* __restrict__ a_src,
    float* __restrict__ a_dst, int N)
{
    int t = threadIdx.x;
    int wv = t >> 6, lane = t & 63;
    long n = (long)blockIdx.x * 4 + wv;
    if (n >= N) return;
    if (H == 4) {
        ushort4 u = *(const ushort4*)&xsb[n * 256 + lane * 4];
        float4 as = *(const float4*)&att_s[lane * 4];
        float4 ad = *(const float4*)&att_d[lane * 4];
        float x0 = bf1(u.x), x1 = bf1(u.y), x2 = bf1(u.z), x3 = bf1(u.w);
        float p = x0 * as.x + x1 * as.y + x2 * as.z + x3 * as.w;
        float q = x0 * ad.x + x1 * ad.y + x2 * ad.z + x3 * ad.w;
#pragma unroll
        for (int k = 8; k; k >>= 1) {
            p += __shfl_xor(p, k, 64);
            q += __shfl_xor(q, k, 64);
        }
        if ((lane & 15) == 0) {
            a_src[n * 4 + (lane >> 4)] = p;
            a_dst[n * 4 + (lane >> 4)] = q;
        }
    } else {
        float x = bf1(xsb[n * 64 + lane]);
        float p = x * att_s[lane];
        float q = x * att_d[lane];
#pragma unroll
        for (int k = 32; k; k >>= 1) {
            p += __shfl_xor(p, k, 64);
            q += __shfl_xor(q, k, 64);
        }
        if (lane == 0) { a_src[n] = p; a_dst[n] = q; }
    }
}

// ---------------------------------------------------------------- CSR build
__global__ __launch_bounds__(256) void k_count(
    const int* __restrict__ dst, const int* __restrict__ et,
    int* __restrict__ cnt_t, int E)
{
    int e = blockIdx.x * 256 + threadIdx.x;
    if (e < E) atomicAdd(&cnt_t[dst[e] * 4 + et[e]], 1);
}

__global__ __launch_bounds__(256) void k_scan1(
    const int* __restrict__ cnt_t, int* __restrict__ row_off,
    int* __restrict__ blk_sums, int N)
{
    __shared__ int s[256];
    int t = threadIdx.x;
    int i = blockIdx.x * 256 + t;
    int v = 0;
    if (i < N) v = cnt_t[4 * i] + cnt_t[4 * i + 1] + cnt_t[4 * i + 2] + cnt_t[4 * i + 3];
    s[t] = v;
    __syncthreads();
    for (int off = 1; off < 256; off <<= 1) {
        int x = 0;
        if (t >= off) x = s[t - off];
        __syncthreads();
        s[t] += x;
        __syncthreads();
    }
    if (i < N) row_off[i] = s[t] - v;
    if (t == 255) blk_sums[blockIdx.x] = s[255];
}

__global__ __launch_bounds__(256) void k_scan2(int* __restrict__ blk_sums, int nb)
{
    __shared__ int s[256];
    int t = threadIdx.x;
    int v = (t < nb) ? blk_sums[t] : 0;
    s[t] = v;
    __syncthreads();
    for (int off = 1; off < 256; off <<= 1) {
        int x = 0;
        if (t >= off) x = s[t - off];
        __syncthreads();
        s[t] += x;
        __syncthreads();
    }
    if (t < nb) blk_sums[t] = s[t] - v;
}

__global__ __launch_bounds__(256) void k_scan3(
    int* __restrict__ row_off, int* __restrict__ cursor,
    const int* __restrict__ blk_sums, int N, int E)
{
    int t = threadIdx.x;
    int i = blockIdx.x * 256 + t;
    if (i < N) {
        int o = row_off[i] + blk_sums[blockIdx.x];
        row_off[i] = o;
        cursor[i] = o;
    }
    if (i == 0) row_off[N] = E;
}

__global__ __launch_bounds__(256) void k_scatter(
    const int* __restrict__ src, const int* __restrict__ dst,
    const int* __restrict__ et, int* __restrict__ cursor,
    int* __restrict__ csr_pack, int E)
{
    int e = blockIdx.x * 256 + threadIdx.x;
    if (e < E) {
        int d = dst[e];
        int pos = atomicAdd(&cursor[d], 1);
        csr_pack[pos] = src[e] | (et[e] << 28);
    }
}

// ---------------- GAT layer 1: 128 thr = 2 waves; wave w owns heads 2w,2w+1.
__global__ __launch_bounds__(128) void k_gat1(
    const unsigned short* __restrict__ xs1b, const float* __restrict__ a_src,
    const float* __restrict__ a_dst, const int* __restrict__ row_off,
    const int* __restrict__ csr_pack,
    const int* __restrict__ cnt_t, const float* __restrict__ aet1,
    const float* __restrict__ ln_g, const float* __restrict__ ln_b,
    float* io)
{
    __shared__ __align__(16) float4 ws[2][64];
    __shared__ float2 aetp[2][4];
    __shared__ float red[4];
    int n = blockIdx.x;
    int t = threadIdx.x;
    int w = t >> 6, c = t & 63;
    int h0 = 2 * w;
    if (t < 8) {
        int w2 = t >> 2, ty = t & 3;
        aetp[w2][ty] = make_float2(aet1[ty * 4 + 2 * w2], aet1[ty * 4 + 2 * w2 + 1]);
    }
    int off = row_off[n], deg = row_off[n + 1] - off;
    float2 a_d = *(const float2*)&a_dst[n * 4 + h0];
    __syncthreads();
    float ael0 = 0.f, ael1 = 0.f;
    int degc = 0;
#pragma unroll
    for (int ty = 0; ty < 4; ++ty) {
        int ct = cnt_t[n * 4 + ty];
        degc += ct;
        float2 ae = aetp[w][ty];
        ael0 += (float)ct * ae.x;
        ael1 += (float)ct * ae.y;
    }
    float inv = (degc > 0) ? 1.f / (float)degc : 1.f;
    float2 a_s_self = *(const float2*)&a_src[n * 4 + h0];
    float al0 = a_s_self.x + a_d.x + ael0 * inv;
    float al1 = a_s_self.y + a_d.y + ael1 * inv;
    al0 = LRELU(al0); al1 = LRELU(al1);
    float wself0 = expf(al0), wself1 = expf(al1);
    int col = w * 128 + 2 * c;
    unsigned int uself = *(const unsigned int*)&xs1b[(long)n * 256 + col];
    float wself_l = (c < 32) ? wself0 : wself1;
    float acc0 = wself_l * bflo(uself);
    float acc1 = wself_l * bfhi(uself);
    float dp0 = 0.f, dp1 = 0.f;
    const unsigned short* xcol = xs1b + col;
    for (int base = 0; base < deg; base += 64) {
        int cnt = min(64, deg - base);
        if (c < cnt) {
            int pk = csr_pack[off + base + c];
            int s = pk & 0x0FFFFFFF;
            int ty = ((unsigned)pk) >> 28;
            float2 as2 = *(const float2*)&a_src[s * 4 + h0];
            float2 ae = aetp[w][ty];
            float a0 = as2.x + a_d.x + ae.x;
            float a1 = as2.y + a_d.y + ae.y;
            a0 = LRELU(a0); a1 = LRELU(a1);
            float w0 = expf(a0), w1 = expf(a1);
            dp0 += w0; dp1 += w1;
            ws[w][c] = make_float4(w0, w1, __int_as_float(s), 0.f);
        }
        int i = 0;
        float b00 = 0.f, b01 = 0.f, b10 = 0.f, b11 = 0.f;
        for (; i + 2 <= cnt; i += 2) {
            float4 p0 = ws[w][i];
            float4 p1 = ws[w][i + 1];
            unsigned int u0 = *(const unsigned int*)&xcol[(long)__float_as_int(p0.z) * 256];
            unsigned int u1 = *(const unsigned int*)&xcol[(long)__float_as_int(p1.z) * 256];
            float w0 = (c < 32) ? p0.x : p0.y;
            float w1 = (c < 32) ? p1.x : p1.y;
            b00 += w0 * bflo(u0); b01 += w0 * bfhi(u0);
            b10 += w1 * bflo(u1); b11 += w1 * bfhi(u1);
        }
        if (i < cnt) {
            float4 p = ws[w][i];
            unsigned int u = *(const unsigned int*)&xcol[(long)__float_as_int(p.z) * 256];
            float w0 = (c < 32) ? p.x : p.y;
            b00 += w0 * bflo(u); b01 += w0 * bfhi(u);
        }
        acc0 += b00 + b10;
        acc1 += b01 + b11;
    }
#pragma unroll
    for (int k = 32; k; k >>= 1) {
        dp0 += __shfl_xor(dp0, k, 64);
        dp1 += __shfl_xor(dp1, k, 64);
    }
    float dsum = ((c < 32) ? dp0 + wself0 : dp1 + wself1) + 1e-16f;
    float2 res = *(const float2*)&io[(long)n * 256 + col];
    float v0 = acc0 / dsum + res.x;
    float v1 = acc1 / dsum + res.y;
    float s1 = v0 + v1, s2 = v0 * v0 + v1 * v1;
#pragma unroll
    for (int k = 32; k; k >>= 1) {
        s1 += __shfl_xor(s1, k, 64);
        s2 += __shfl_xor(s2, k, 64);
    }
    if (c == 0) { red[w] = s1; red[2 + w] = s2; }
    __syncthreads();
    float mu = (red[0] + red[1]) * (1.f / 256.f);
    float var = (red[2] + red[3]) * (1.f / 256.f) - mu * mu;
    float rs = rsqrtf(var + 1e-5f);
    float2 g = *(const float2*)&ln_g[col];
    float2 bln = *(const float2*)&ln_b[col];
    float y0 = fmaxf((v0 - mu) * rs * g.x + bln.x, 0.f);
    float y1 = fmaxf((v1 - mu) * rs * g.y + bln.y, 0.f);
    *(float2*)&io[(long)n * 256 + col] = make_float2(y0, y1);
}

// --------------------------------- GAT layer 2 (H=1, C=64): one wave per node
__global__ __launch_bounds__(64) void k_gat2(
    const unsigned short* __restrict__ xs2b, const float* __restrict__ a_src,
    const float* __restrict__ a_dst, const int* __restrict__ row_off,
    const int* __restrict__ csr_pack,
    const int* __restrict__ cnt_t, const float* __restrict__ aet2,
    const float* __restrict__ ln_g, const float* __restrict__ ln_b,
    float* io)
{
    __shared__ __align__(8) float2 ws[64];
    __shared__ float aetl[4];
    int n = blockIdx.x;
    int c = threadIdx.x;
    if (c < 4) aetl[c] = aet2[c];
    int off = row_off[n], deg = row_off[n + 1] - off;
    float a_d = a_dst[n];
    float ael = 0.f;
    int degc = 0;
#pragma unroll
    for (int ty = 0; ty < 4; ++ty) {
        int ct = cnt_t[n * 4 + ty];
        degc += ct;
        ael += (float)ct * aet2[ty];
    }
    ael *= (degc > 0 ? 1.f / (float)degc : 1.f);
    float al = a_src[n] + a_d + ael;
    al = LRELU(al);
    float wself = expf(al);
    float acc = wself * bf1(xs2b[(long)n * 64 + c]);
    float dp = 0.f;
    const unsigned short* xcol = xs2b + c;
    for (int base = 0; base < deg; base += 64) {
        int cnt = min(64, deg - base);
        if (c < cnt) {
            int pk = csr_pack[off + base + c];
            int s = pk & 0x0FFFFFFF;
            int ty = ((unsigned)pk) >> 28;
            float a = a_src[s] + a_d + aetl[ty];
            a = LRELU(a);
            float we = expf(a);
            dp += we;
            ws[c] = make_float2(we, __int_as_float(s));
        }
        int i = 0;
        float b0 = 0.f, b1 = 0.f;
        for (; i + 2 <= cnt; i += 2) {
            float2 p0 = ws[i];
            float2 p1 = ws[i + 1];
            b0 += p0.x * bf1(xcol[(long)__float_as_int(p0.y) * 64]);
            b1 += p1.x * bf1(xcol[(long)__float_as_int(p1.y) * 64]);
        }
        if (i < cnt) {
            float2 p = ws[i];
            b0 += p.x * bf1(xcol[(long)__float_as_int(p.y) * 64]);
        }
        acc += b0 + b1;
    }
#pragma unroll
    for (int k = 32; k; k >>= 1) dp += __shfl_xor(dp, k, 64);
    float dsum = dp + wself + 1e-16f;
    float v = acc / dsum + io[(long)n * 64 + c];
    float s1 = v, s2 = v * v;
#pragma unroll
    for (int k = 32; k; k >>= 1) {
        s1 += __shfl_xor(s1, k, 64);
        s2 += __shfl_xor(s2, k, 64);
    }
    float mu = s1 * (1.f / 64.f);
    float var = s2 * (1.f / 64.f) - mu * mu;
    io[(long)n * 64 + c] = (v - mu) * rsqrtf(var + 1e-5f) * ln_g[c] + ln_b[c];
}

// --------------------------------------------------------------- classifier
__global__ __launch_bounds__(256) void k_cls(
    const float* __restrict__ hid2, const int* __restrict__ asp,
    const float* __restrict__ w, const float* __restrict__ b,
    float* __restrict__ out)
{
    int g = blockIdx.x * 256 + threadIdx.x;
    int i = g / 3, j = g - i * 3;
    int a = asp[i];
    float acc = b[j];
#pragma unroll 8
    for (int cc = 0; cc < 64; ++cc) acc += hid2[(long)a * 64 + cc] * w[cc * 3 + j];
    out[i * 3 + j] = acc;
}

extern "C" void kernel_launch(void* const* d_in, const int* in_sizes, int n_in,
                              void* d_out, int out_size, void* d_ws, size_t ws_size,
                              hipStream_t stream)
{
    const float* features    = (const float*)d_in[0];
    const int*   edge_index  = (const int*)d_in[1];
    const int*   aspect      = (const int*)d_in[2];
    const int*   etypes      = (const int*)d_in[3];
    const int*   ntypes      = (const int*)d_in[4];
    const float* pos         = (const float*)d_in[5];
    const float* fe_w1       = (const float*)d_in[6];
    const float* fe_b1       = (const float*)d_in[7];
    const float* fe_w2       = (const float*)d_in[8];
    const float* fe_b2       = (const float*)d_in[9];
    const float* fe_pos_w    = (const float*)d_in[10];
    const float* fe_pos_b    = (const float*)d_in[11];
    const float* fe_type_emb = (const float*)d_in[12];
    const float* fe_out_w    = (const float*)d_in[13];
    const float* fe_out_b    = (const float*)d_in[14];
    const float* g1_lin_w    = (const float*)d_in[15];
    const float* g1_att_src  = (const float*)d_in[16];
    const float* g1_att_dst  = (const float*)d_in[17];
    const float* g1_edge_emb = (const float*)d_in[18];
    const float* g1_lin_edge = (const float*)d_in[19];
    const float* g1_att_edge = (const float*)d_in[20];
    const float* g1_bias     = (const float*)d_in[21];
    const float* g1_res_w    = (const float*)d_in[22];
    const float* g1_res_b    = (const float*)d_in[23];
    const float* g1_ln_g     = (const float*)d_in[24];
    const float* g1_ln_b     = (const float*)d_in[25];
    const float* g2_lin_w    = (const float*)d_in[26];
    const float* g2_att_src  = (const float*)d_in[27];
    const float* g2_att_dst  = (const float*)d_in[28];
    const float* g2_edge_emb = (const float*)d_in[29];
    const float* g2_lin_edge = (const float*)d_in[30];
    const float* g2_att_edge = (const float*)d_in[31];
    const float* g2_bias     = (const float*)d_in[32];
    const float* g2_res_w    = (const float*)d_in[33];
    const float* g2_res_b    = (const float*)d_in[34];
    const float* g2_ln_g     = (const float*)d_in[35];
    const float* g2_ln_b     = (const float*)d_in[36];
    const float* cls_w       = (const float*)d_in[37];
    const float* cls_b       = (const float*)d_in[38];

    const int N = in_sizes[0] / 768;   // 50000
    const int E = in_sizes[1] / 2;     // 800000
    const int* src = edge_index;
    const int* dst = edge_index + E;

    char* wsb = (char*)d_ws;
    size_t off = 0;
    auto alloc = [&](size_t bytes) -> char* {
        char* p = wsb + off;
        off += (bytes + 255) & ~(size_t)255;
        return p;
    };
    float* t1      = (float*)alloc((size_t)N * 64 * 4);
    float* hfe     = (float*)alloc((size_t)N * 64 * 4);
    unsigned short* xs1b = (unsigned short*)alloc((size_t)N * 256 * 2);
    unsigned short* xs2b = (unsigned short*)alloc((size_t)N * 64 * 2);
    float* rp1     = (float*)alloc((size_t)N * 256 * 4);  // res_pre1, then hid1
    float* rp2     = (float*)alloc((size_t)N * 64 * 4);   // res_pre2, then hid2
    float* a_src1  = (float*)alloc((size_t)N * 4 * 4);
    float* a_dst1  = (float*)alloc((size_t)N * 4 * 4);
    float* a_src2  = (float*)alloc((size_t)N * 4);
    float* a_dst2  = (float*)alloc((size_t)N * 4);
    int*   cnt_t   = (int*)alloc((size_t)N * 4 * 4);
    int*   row_off = (int*)alloc((size_t)(N + 1) * 4);
    int*   cursor  = (int*)alloc((size_t)N * 4);
    int*   blk     = (int*)alloc(1024);
    int*   csr_pack= (int*)alloc((size_t)E * 4);
    float* aet1    = (float*)alloc(64);
    float* aet2    = (float*)alloc(64);

    hipMemsetAsync(cnt_t, 0, (size_t)N * 4 * 4, stream);

    int mb = (N + 63) / 64;   // 782 row-tiles
    int ab = (N + 3) / 4;     // k_att blocks

    k_tables<<<1, 64, 0, stream>>>(g1_edge_emb, g1_lin_edge, g1_att_edge,
                                   g2_edge_emb, g2_lin_edge, g2_att_edge, aet1, aet2);
    k_fe1<<<mb, 256, 0, stream>>>(features, fe_w1, fe_b1, t1, N);
    k_fe2<<<N / 4, 256, 0, stream>>>(t1, fe_w2, fe_b2, ntypes, fe_type_emb, pos,
                                     fe_pos_w, fe_pos_b, fe_out_w, fe_out_b, hfe);
    // layer-1 prep: hfe[Nx64] @ [lin|res][64x512] -> xs1b bf16 + rp1 fp32
    k_prep_gemm<64, 256><<<dim3(mb, 4), 256, 0, stream>>>(
        hfe, g1_lin_w, g1_res_w, g1_bias, g1_res_b, xs1b, rp1, N);
    k_att<4><<<ab, 256, 0, stream>>>(xs1b, g1_att_src, g1_att_dst, a_src1, a_dst1, N);
    int eblk = (E + 255) / 256;
    int nb = (N + 255) / 256;
    k_count<<<eblk, 256, 0, stream>>>(dst, etypes, cnt_t, E);
    k_scan1<<<nb, 256, 0, stream>>>(cnt_t, row_off, blk, N);
    k_scan2<<<1, 256, 0, stream>>>(blk, nb);
    k_scan3<<<nb, 256, 0, stream>>>(row_off, cursor, blk, N, E);
    k_scatter<<<eblk, 256, 0, stream>>>(src, dst, etypes, cursor, csr_pack, E);
    k_gat1<<<N, 128, 0, stream>>>(xs1b, a_src1, a_dst1, row_off, csr_pack,
                                  cnt_t, aet1, g1_ln_g, g1_ln_b, rp1);
    // layer-2 prep: hid1[Nx256] @ [lin|res][256x128] -> xs2b bf16 + rp2 fp32
    k_prep_gemm<256, 64><<<dim3(mb, 1), 256, 0, stream>>>(
        rp1, g2_lin_w, g2_res_w, g2_bias, g2_res_b, xs2b, rp2, N);
    k_att<1><<<ab, 256, 0, stream>>>(xs2b, g2_att_src, g2_att_dst, a_src2, a_dst2, N);
    k_gat2<<<N, 64, 0, stream>>>(xs2b, a_src2, a_dst2, row_off, csr_pack,
                                 cnt_t, aet2, g2_ln_g, g2_ln_b, rp2);
    k_cls<<<(out_size + 255) / 256, 256, 0, stream>>>(rp2, aspect, cls_w, cls_b,
                                                      (float*)d_out);
}

// Round 7
// 638.699 us; speedup vs baseline: 1.8542x; 1.0949x over previous
//
#include <hip/hip_runtime.h>

// SimplifiedHAFE on MI355X — round 6: staging diet + gather ILP.
//  (a) All GEMM B matrices pre-swizzled to MFMA-fragment-order bf16 by tiny
//      one-off kernels; hot GEMM loops read B frags directly from L2 (no B
//      LDS, no B conversion). A-staging converts fp32->bf16 via v_perm_b32
//      pack (+0x8000 round-half-up), 2 ds_write_b128 per thread per chunk.
//  (b) gat1/gat2 aggregation unrolled 8x with zero-weight padding -> ~8
//      outstanding gathers (was ~2), hiding L2/L3 latency.
// Round-6 profile: k_gat1 98 us (VALU 63%, HBM 39%); k_fe1 hidden ~95 us,
// conversion/staging-ALU-bound (~100 VALU per 8 MFMA in K-loop).

#define LRELU(x) ((x) > 0.f ? (x) : 0.2f * (x))

typedef __attribute__((ext_vector_type(8))) short short8;
typedef __attribute__((ext_vector_type(4))) float floatx4;

__device__ __forceinline__ unsigned short f2bf(float x) {
    union { float f; unsigned int u; } v; v.f = x;
    unsigned int r = (v.u + 0x7FFFu + ((v.u >> 16) & 1u)) >> 16;  // RNE
    return (unsigned short)r;
}
// pack 2 fp32 -> 2 bf16 (round-half-up) in ~3 VALU via v_perm_b32
__device__ __forceinline__ unsigned int pkbf(float lo, float hi) {
    unsigned int a = __float_as_uint(lo) + 0x8000u;
    unsigned int b = __float_as_uint(hi) + 0x8000u;
    return __builtin_amdgcn_perm(b, a, 0x07060302u);
}
__device__ __forceinline__ float bflo(unsigned int u) {
    return __uint_as_float(u << 16);
}
__device__ __forceinline__ float bfhi(unsigned int u) {
    return __uint_as_float(u & 0xFFFF0000u);
}
__device__ __forceinline__ float bf1(unsigned short u) {
    return __uint_as_float(((unsigned int)u) << 16);
}

// ---------------------------------------------------------------- tiny tables
__global__ __launch_bounds__(64) void k_tables(
    const float* __restrict__ e_emb1, const float* __restrict__ lew1,
    const float* __restrict__ ae1,
    const float* __restrict__ e_emb2, const float* __restrict__ lew2,
    const float* __restrict__ ae2,
    float* __restrict__ aet1, float* __restrict__ aet2)
{
    __shared__ float M1[16];
    __shared__ float M2[4];
    int t = threadIdx.x;
    if (t < 16) {
        int d = t >> 2, h = t & 3;
        float s = 0.f;
        for (int c = 0; c < 64; ++c) s += lew1[d * 256 + h * 64 + c] * ae1[h * 64 + c];
        M1[d * 4 + h] = s;
    }
    if (t < 4) {
        float s = 0.f;
        for (int c = 0; c < 64; ++c) s += lew2[t * 64 + c] * ae2[c];
        M2[t] = s;
    }
    __syncthreads();
    if (t < 16) {
        int ty = t >> 2, h = t & 3;
        float s = 0.f;
        for (int d = 0; d < 4; ++d) s += e_emb1[ty * 4 + d] * M1[d * 4 + h];
        aet1[ty * 4 + h] = s;
    }
    if (t < 4) {
        float s = 0.f;
        for (int d = 0; d < 4; ++d) s += e_emb2[t * 4 + d] * M2[d];
        aet2[t] = s;
    }
}

// ----------------- B pre-swizzle: fe1 weight (768x64) -> frag-order bf16
__global__ __launch_bounds__(256) void k_bswz_fe1(
    const float* __restrict__ w1, unsigned short* __restrict__ out)
{
    for (int idx = blockIdx.x * 256 + threadIdx.x; idx < 768 * 64;
         idx += gridDim.x * 256) {
        int k = idx >> 6, col = idx & 63;
        int c = k >> 6, kl = k & 63, kg = kl >> 3, j = kl & 7;
        out[((c * 8 + kg) * 64 + col) * 8 + j] = f2bf(w1[k * 64 + col]);
    }
}

// --------- B pre-swizzle: concat [B1|B2] (Kx2NH) -> frag-order, 128-col tiles
template<int K, int NH>
__global__ __launch_bounds__(256) void k_bswz2(
    const float* __restrict__ B1, const float* __restrict__ B2,
    unsigned short* __restrict__ out)
{
    const int NC = 2 * NH;
    for (int idx = blockIdx.x * 256 + threadIdx.x; idx < K * NC;
         idx += gridDim.x * 256) {
        int k = idx / NC, col = idx % NC;
        float v = (col < NH) ? B1[k * NH + col] : B2[k * NH + col - NH];
        int c = k >> 6, kl = k & 63, kg = kl >> 3, j = kl & 7;
        int ct = col >> 7, cl = col & 127;
        out[(((c * (NC / 128) + ct) * 8 + kg) * 128 + cl) * 8 + j] = f2bf(v);
    }
}

// ------------------ FE stage 1: relu(X@W1+b1), bf16 MFMA, pre-swizzled B
__global__ __launch_bounds__(256) void k_fe1(
    const float* __restrict__ feat, const unsigned short* __restrict__ bswz,
    const float* __restrict__ b1, float* __restrict__ t1, int N)
{
    __shared__ __align__(16) unsigned short A_lds[8 * 64 * 8];  // 8 KiB
    int t = threadIdx.x;
    int wv = t >> 6, lane = t & 63;
    int quad = lane >> 4, l16 = lane & 15;
    long n0 = (long)blockIdx.x * 64;

    floatx4 acc[4];
#pragma unroll
    for (int i = 0; i < 4; ++i) acc[i] = (floatx4){0.f, 0.f, 0.f, 0.f};

    int srow = t >> 2, sf4 = t & 3;
    long arow = n0 + srow;
    if (arow >= N) arow = N - 1;
    const float* fbase = feat + arow * 768 + sf4 * 16;
    int col = wv * 16 + l16;

    for (int kc = 0; kc < 768; kc += 64) {
        __syncthreads();
        // stage A: 16 consecutive k per thread -> 2 b128 writes
        float4 v0 = *(const float4*)(fbase + kc);
        float4 v1 = *(const float4*)(fbase + kc + 4);
        float4 v2 = *(const float4*)(fbase + kc + 8);
        float4 v3 = *(const float4*)(fbase + kc + 12);
        uint4 w0 = {pkbf(v0.x, v0.y), pkbf(v0.z, v0.w),
                    pkbf(v1.x, v1.y), pkbf(v1.z, v1.w)};
        uint4 w1p = {pkbf(v2.x, v2.y), pkbf(v2.z, v2.w),
                     pkbf(v3.x, v3.y), pkbf(v3.z, v3.w)};
        *(uint4*)&A_lds[((2 * sf4) * 64 + srow) * 8] = w0;
        *(uint4*)&A_lds[((2 * sf4 + 1) * 64 + srow) * 8] = w1p;
        __syncthreads();
        int ci = kc >> 6;
#pragma unroll
        for (int s = 0; s < 2; ++s) {
            int kg0 = s * 4 + quad;
            short8 bfrag = *(const short8*)&bswz[((ci * 8 + kg0) * 64 + col) * 8];
#pragma unroll
            for (int mt = 0; mt < 4; ++mt) {
                short8 afrag = *(const short8*)&A_lds[(kg0 * 64 + mt * 16 + l16) * 8];
                acc[mt] = __builtin_amdgcn_mfma_f32_16x16x32_bf16(
                    afrag, bfrag, acc[mt], 0, 0, 0);
            }
        }
    }
    float bb = b1[col];
#pragma unroll
    for (int mt = 0; mt < 4; ++mt) {
#pragma unroll
        for (int r = 0; r < 4; ++r) {
            long m = n0 + mt * 16 + quad * 4 + r;
            if (m < N) t1[m * 64 + col] = fmaxf(acc[mt][r] + bb, 0.f);
        }
    }
}

// ------------------------- FE tail: (@W2+b2 + emb + pos terms) @ out_w + b
__global__ __launch_bounds__(256) void k_fe2(
    const float* __restrict__ t1, const float* __restrict__ w2,
    const float* __restrict__ b2, const int* __restrict__ ntypes,
    const float* __restrict__ temb, const float* __restrict__ pos,
    const float* __restrict__ posw, const float* __restrict__ posb,
    const float* __restrict__ outw, const float* __restrict__ outb,
    float* __restrict__ hfe)
{
    __shared__ float l1[256];
    __shared__ float l2[256];
    int t = threadIdx.x;
    long base = (long)blockIdx.x * 256;
    l1[t] = t1[base + t];
    __syncthreads();
    int r = t >> 6, c = t & 63;
    float acc = 0.f;
#pragma unroll 8
    for (int k = 0; k < 64; ++k) acc += l1[r * 64 + k] * w2[k * 64 + c];
    long n = (long)blockIdx.x * 4 + r;
    int nt = ntypes[n];
    acc += b2[c] + temb[nt * 64 + c] + pos[n] * posw[c] + posb[c];
    l2[r * 64 + c] = acc;
    __syncthreads();
    float acc2 = 0.f;
#pragma unroll 8
    for (int k = 0; k < 64; ++k) acc2 += l2[r * 64 + k] * outw[k * 64 + c];
    hfe[n * 64 + c] = acc2 + outb[c];
}

// ------- prep GEMM: A[NxK] @ preswizzled [B1|B2][Kx2NH] -> xs bf16 + res fp32
template<int K, int NH>
__global__ __launch_bounds__(256) void k_prep_gemm(
    const float* __restrict__ A, const unsigned short* __restrict__ bswz,
    const float* __restrict__ bias, const float* __restrict__ res_b,
    unsigned short* __restrict__ xsb, float* __restrict__ resp, int N)
{
    constexpr int CT = (2 * NH) / 128;
    __shared__ __align__(16) unsigned short A_lds[8 * 64 * 8];  // 8 KB
    int t = threadIdx.x;
    int wv = t >> 6, lane = t & 63;
    int quad = lane >> 4, l16 = lane & 15;
    long n0 = (long)blockIdx.x * 64;
    int by = blockIdx.y;

    floatx4 acc[4][2];
#pragma unroll
    for (int i = 0; i < 4; ++i)
#pragma unroll
        for (int j = 0; j < 2; ++j) acc[i][j] = (floatx4){0.f, 0.f, 0.f, 0.f};

    int srow = t >> 2, sf4 = t & 3;
    long arow = n0 + srow;
    if (arow >= N) arow = N - 1;
    const float* abase = A + arow * (long)K + sf4 * 16;

    for (int kc = 0; kc < K; kc += 64) {
        __syncthreads();
        float4 v0 = *(const float4*)(abase + kc);
        float4 v1 = *(const float4*)(abase + kc + 4);
        float4 v2 = *(const float4*)(abase + kc + 8);
        float4 v3 = *(const float4*)(abase + kc + 12);
        uint4 w0 = {pkbf(v0.x, v0.y), pkbf(v0.z, v0.w),
                    pkbf(v1.x, v1.y), pkbf(v1.z, v1.w)};
        uint4 w1p = {pkbf(v2.x, v2.y), pkbf(v2.z, v2.w),
                     pkbf(v3.x, v3.y), pkbf(v3.z, v3.w)};
        *(uint4*)&A_lds[((2 * sf4) * 64 + srow) * 8] = w0;
        *(uint4*)&A_lds[((2 * sf4 + 1) * 64 + srow) * 8] = w1p;
        __syncthreads();
        int ci = kc >> 6;
#pragma unroll
        for (int s = 0; s < 2; ++s) {
            int kg0 = s * 4 + quad;
#pragma unroll
            for (int nt = 0; nt < 2; ++nt) {
                short8 bfrag = *(const short8*)&bswz[
                    (((ci * CT + by) * 8 + kg0) * 128 + wv * 32 + nt * 16 + l16) * 8];
#pragma unroll
                for (int mt = 0; mt < 4; ++mt) {
                    short8 afrag = *(const short8*)&A_lds[(kg0 * 64 + mt * 16 + l16) * 8];
                    acc[mt][nt] = __builtin_amdgcn_mfma_f32_16x16x32_bf16(
                        afrag, bfrag, acc[mt][nt], 0, 0, 0);
                }
            }
        }
    }
#pragma unroll
    for (int nt = 0; nt < 2; ++nt) {
        int gc = by * 128 + wv * 32 + nt * 16 + l16;
        bool isl = gc < NH;
        int oc = isl ? gc : gc - NH;
        float badd = isl ? 0.f : (bias[oc] + res_b[oc]);
#pragma unroll
        for (int mt = 0; mt < 4; ++mt) {
#pragma unroll
            for (int r = 0; r < 4; ++r) {
                long m = n0 + mt * 16 + quad * 4 + r;
                if (m < N) {
                    float val = acc[mt][nt][r];
                    if (isl) xsb[m * NH + oc] = f2bf(val);
                    else     resp[m * NH + oc] = val + badd;
                }
            }
        }
    }
}

// --------- attention scalars: a_src/a_dst[n,h] = dot(xs[n,h*64:+64], att)
template<int H>
__global__ __launch_bounds__(256) void k_att(
    const unsigned short* __restrict__ xsb, const float* __restrict__ att_s,
    const float* __restrict__ att_d, float* __restrict__ a_src,
    float* __restrict__ a_dst, int N)
{
    int t = threadIdx.x;
    int wv = t >> 6, lane = t & 63;
    long n = (long)blockIdx.x * 4 + wv;
    if (n >= N) return;
    if (H == 4) {
        ushort4 u = *(const ushort4*)&xsb[n * 256 + lane * 4];
        float4 as = *(const float4*)&att_s[lane * 4];
        float4 ad = *(const float4*)&att_d[lane * 4];
        float x0 = bf1(u.x), x1 = bf1(u.y), x2 = bf1(u.z), x3 = bf1(u.w);
        float p = x0 * as.x + x1 * as.y + x2 * as.z + x3 * as.w;
        float q = x0 * ad.x + x1 * ad.y + x2 * ad.z + x3 * ad.w;
#pragma unroll
        for (int k = 8; k; k >>= 1) {
            p += __shfl_xor(p, k, 64);
            q += __shfl_xor(q, k, 64);
        }
        if ((lane & 15) == 0) {
            a_src[n * 4 + (lane >> 4)] = p;
            a_dst[n * 4 + (lane >> 4)] = q;
        }
    } else {
        float x = bf1(xsb[n * 64 + lane]);
        float p = x * att_s[lane];
        float q = x * att_d[lane];
#pragma unroll
        for (int k = 32; k; k >>= 1) {
            p += __shfl_xor(p, k, 64);
            q += __shfl_xor(q, k, 64);
        }
        if (lane == 0) { a_src[n] = p; a_dst[n] = q; }
    }
}

// ---------------------------------------------------------------- CSR build
__global__ __launch_bounds__(256) void k_count(
    const int* __restrict__ dst, const int* __restrict__ et,
    int* __restrict__ cnt_t, int E)
{
    int e = blockIdx.x * 256 + threadIdx.x;
    if (e < E) atomicAdd(&cnt_t[dst[e] * 4 + et[e]], 1);
}

__global__ __launch_bounds__(256) void k_scan1(
    const int* __restrict__ cnt_t, int* __restrict__ row_off,
    int* __restrict__ blk_sums, int N)
{
    __shared__ int s[256];
    int t = threadIdx.x;
    int i = blockIdx.x * 256 + t;
    int v = 0;
    if (i < N) v = cnt_t[4 * i] + cnt_t[4 * i + 1] + cnt_t[4 * i + 2] + cnt_t[4 * i + 3];
    s[t] = v;
    __syncthreads();
    for (int off = 1; off < 256; off <<= 1) {
        int x = 0;
        if (t >= off) x = s[t - off];
        __syncthreads();
        s[t] += x;
        __syncthreads();
    }
    if (i < N) row_off[i] = s[t] - v;
    if (t == 255) blk_sums[blockIdx.x] = s[255];
}

__global__ __launch_bounds__(256) void k_scan2(int* __restrict__ blk_sums, int nb)
{
    __shared__ int s[256];
    int t = threadIdx.x;
    int v = (t < nb) ? blk_sums[t] : 0;
    s[t] = v;
    __syncthreads();
    for (int off = 1; off < 256; off <<= 1) {
        int x = 0;
        if (t >= off) x = s[t - off];
        __syncthreads();
        s[t] += x;
        __syncthreads();
    }
    if (t < nb) blk_sums[t] = s[t] - v;
}

__global__ __launch_bounds__(256) void k_scan3(
    int* __restrict__ row_off, int* __restrict__ cursor,
    const int* __restrict__ blk_sums, int N, int E)
{
    int t = threadIdx.x;
    int i = blockIdx.x * 256 + t;
    if (i < N) {
        int o = row_off[i] + blk_sums[blockIdx.x];
        row_off[i] = o;
        cursor[i] = o;
    }
    if (i == 0) row_off[N] = E;
}

__global__ __launch_bounds__(256) void k_scatter(
    const int* __restrict__ src, const int* __restrict__ dst,
    const int* __restrict__ et, int* __restrict__ cursor,
    int* __restrict__ csr_pack, int E)
{
    int e = blockIdx.x * 256 + threadIdx.x;
    if (e < E) {
        int d = dst[e];
        int pos = atomicAdd(&cursor[d], 1);
        csr_pack[pos] = src[e] | (et[e] << 28);
    }
}

// ---------------- GAT layer 1: 128 thr = 2 waves; wave w owns heads 2w,2w+1.
__global__ __launch_bounds__(128) void k_gat1(
    const unsigned short* __restrict__ xs1b, const float* __restrict__ a_src,
    const float* __restrict__ a_dst, const int* __restrict__ row_off,
    const int* __restrict__ csr_pack,
    const int* __restrict__ cnt_t, const float* __restrict__ aet1,
    const float* __restrict__ ln_g, const float* __restrict__ ln_b,
    float* io)
{
    __shared__ __align__(16) float4 ws[2][64];
    __shared__ float2 aetp[2][4];
    __shared__ float red[4];
    int n = blockIdx.x;
    int t = threadIdx.x;
    int w = t >> 6, c = t & 63;
    int h0 = 2 * w;
    if (t < 8) {
        int w2 = t >> 2, ty = t & 3;
        aetp[w2][ty] = make_float2(aet1[ty * 4 + 2 * w2], aet1[ty * 4 + 2 * w2 + 1]);
    }
    int off = row_off[n], deg = row_off[n + 1] - off;
    float2 a_d = *(const float2*)&a_dst[n * 4 + h0];
    __syncthreads();
    float ael0 = 0.f, ael1 = 0.f;
    int degc = 0;
#pragma unroll
    for (int ty = 0; ty < 4; ++ty) {
        int ct = cnt_t[n * 4 + ty];
        degc += ct;
        float2 ae = aetp[w][ty];
        ael0 += (float)ct * ae.x;
        ael1 += (float)ct * ae.y;
    }
    float inv = (degc > 0) ? 1.f / (float)degc : 1.f;
    float2 a_s_self = *(const float2*)&a_src[n * 4 + h0];
    float al0 = a_s_self.x + a_d.x + ael0 * inv;
    float al1 = a_s_self.y + a_d.y + ael1 * inv;
    al0 = LRELU(al0); al1 = LRELU(al1);
    float wself0 = expf(al0), wself1 = expf(al1);
    int col = w * 128 + 2 * c;
    unsigned int uself = *(const unsigned int*)&xs1b[(long)n * 256 + col];
    float wself_l = (c < 32) ? wself0 : wself1;
    float acc0 = wself_l * bflo(uself);
    float acc1 = wself_l * bfhi(uself);
    float dp0 = 0.f, dp1 = 0.f;
    const unsigned short* xcol = xs1b + col;
    for (int base = 0; base < deg; base += 64) {
        int cnt = min(64, deg - base);
        float w0 = 0.f, w1 = 0.f;
        int s = 0;
        if (c < cnt) {
            int pk = csr_pack[off + base + c];
            s = pk & 0x0FFFFFFF;
            int ty = ((unsigned)pk) >> 28;
            float2 as2 = *(const float2*)&a_src[s * 4 + h0];
            float2 ae = aetp[w][ty];
            float a0 = as2.x + a_d.x + ae.x;
            float a1 = as2.y + a_d.y + ae.y;
            a0 = LRELU(a0); a1 = LRELU(a1);
            w0 = expf(a0); w1 = expf(a1);
        }
        dp0 += w0; dp1 += w1;
        ws[w][c] = make_float4(w0, w1, __int_as_float(s), 0.f);
        // wave-private LDS; zero-weight-padded batches of 8 for gather ILP
        int cr = (cnt + 7) & ~7;
        for (int i = 0; i < cr; i += 8) {
#pragma unroll
            for (int u = 0; u < 8; ++u) {
                float4 p = ws[w][i + u];
                unsigned int uu = *(const unsigned int*)&xcol[
                    (long)__float_as_int(p.z) * 256];
                float wl = (c < 32) ? p.x : p.y;
                acc0 += wl * bflo(uu);
                acc1 += wl * bfhi(uu);
            }
        }
    }
#pragma unroll
    for (int k = 32; k; k >>= 1) {
        dp0 += __shfl_xor(dp0, k, 64);
        dp1 += __shfl_xor(dp1, k, 64);
    }
    float dsum = ((c < 32) ? dp0 + wself0 : dp1 + wself1) + 1e-16f;
    float2 res = *(const float2*)&io[(long)n * 256 + col];
    float v0 = acc0 / dsum + res.x;
    float v1 = acc1 / dsum + res.y;
    float s1 = v0 + v1, s2 = v0 * v0 + v1 * v1;
#pragma unroll
    for (int k = 32; k; k >>= 1) {
        s1 += __shfl_xor(s1, k, 64);
        s2 += __shfl_xor(s2, k, 64);
    }
    if (c == 0) { red[w] = s1; red[2 + w] = s2; }
    __syncthreads();
    float mu = (red[0] + red[1]) * (1.f / 256.f);
    float var = (red[2] + red[3]) * (1.f / 256.f) - mu * mu;
    float rs = rsqrtf(var + 1e-5f);
    float2 g = *(const float2*)&ln_g[col];
    float2 bln = *(const float2*)&ln_b[col];
    float y0 = fmaxf((v0 - mu) * rs * g.x + bln.x, 0.f);
    float y1 = fmaxf((v1 - mu) * rs * g.y + bln.y, 0.f);
    *(float2*)&io[(long)n * 256 + col] = make_float2(y0, y1);
}

// --------------------------------- GAT layer 2 (H=1, C=64): one wave per node
__global__ __launch_bounds__(64) void k_gat2(
    const unsigned short* __restrict__ xs2b, const float* __restrict__ a_src,
    const float* __restrict__ a_dst, const int* __restrict__ row_off,
    const int* __restrict__ csr_pack,
    const int* __restrict__ cnt_t, const float* __restrict__ aet2,
    const float* __restrict__ ln_g, const float* __restrict__ ln_b,
    float* io)
{
    __shared__ __align__(8) float2 ws[64];
    __shared__ float aetl[4];
    int n = blockIdx.x;
    int c = threadIdx.x;
    if (c < 4) aetl[c] = aet2[c];
    int off = row_off[n], deg = row_off[n + 1] - off;
    float a_d = a_dst[n];
    float ael = 0.f;
    int degc = 0;
#pragma unroll
    for (int ty = 0; ty < 4; ++ty) {
        int ct = cnt_t[n * 4 + ty];
        degc += ct;
        ael += (float)ct * aet2[ty];
    }
    ael *= (degc > 0 ? 1.f / (float)degc : 1.f);
    float al = a_src[n] + a_d + ael;
    al = LRELU(al);
    float wself = expf(al);
    float acc = wself * bf1(xs2b[(long)n * 64 + c]);
    float dp = 0.f;
    const unsigned short* xcol = xs2b + c;
    for (int base = 0; base < deg; base += 64) {
        int cnt = min(64, deg - base);
        float we = 0.f;
        int s = 0;
        if (c < cnt) {
            int pk = csr_pack[off + base + c];
            s = pk & 0x0FFFFFFF;
            int ty = ((unsigned)pk) >> 28;
            float a = a_src[s] + a_d + aetl[ty];
            a = LRELU(a);
            we = expf(a);
        }
        dp += we;
        ws[c] = make_float2(we, __int_as_float(s));
        int cr = (cnt + 7) & ~7;
        for (int i = 0; i < cr; i += 8) {
#pragma unroll
            for (int u = 0; u < 8; ++u) {
                float2 p = ws[i + u];
                acc += p.x * bf1(xcol[(long)__float_as_int(p.y) * 64]);
            }
        }
    }
#pragma unroll
    for (int k = 32; k; k >>= 1) dp += __shfl_xor(dp, k, 64);
    float dsum = dp + wself + 1e-16f;
    float v = acc / dsum + io[(long)n * 64 + c];
    float s1 = v, s2 = v * v;
#pragma unroll
    for (int k = 32; k; k >>= 1) {
        s1 += __shfl_xor(s1, k, 64);
        s2 += __shfl_xor(s2, k, 64);
    }
    float mu = s1 * (1.f / 64.f);
    float var = s2 * (1.f / 64.f) - mu * mu;
    io[(long)n * 64 + c] = (v - mu) * rsqrtf(var + 1e-5f) * ln_g[c] + ln_b[c];
}

// --------------------------------------------------------------- classifier
__global__ __launch_bounds__(256) void k_cls(
    const float* __restrict__ hid2, const int* __restrict__ asp,
    const float* __restrict__ w, const float* __restrict__ b,
    float* __restrict__ out)
{
    int g = blockIdx.x * 256 + threadIdx.x;
    int i = g / 3, j = g - i * 3;
    int a = asp[i];
    float acc = b[j];
#pragma unroll 8
    for (int cc = 0; cc < 64; ++cc) acc += hid2[(long)a * 64 + cc] * w[cc * 3 + j];
    out[i * 3 + j] = acc;
}

extern "C" void kernel_launch(void* const* d_in, const int* in_sizes, int n_in,
                              void* d_out, int out_size, void* d_ws, size_t ws_size,
                              hipStream_t stream)
{
    const float* features    = (const float*)d_in[0];
    const int*   edge_index  = (const int*)d_in[1];
    const int*   aspect      = (const int*)d_in[2];
    const int*   etypes      = (const int*)d_in[3];
    const int*   ntypes      = (const int*)d_in[4];
    const float* pos         = (const float*)d_in[5];
    const float* fe_w1       = (const float*)d_in[6];
    const float* fe_b1       = (const float*)d_in[7];
    const float* fe_w2       = (const float*)d_in[8];
    const float* fe_b2       = (const float*)d_in[9];
    const float* fe_pos_w    = (const float*)d_in[10];
    const float* fe_pos_b    = (const float*)d_in[11];
    const float* fe_type_emb = (const float*)d_in[12];
    const float* fe_out_w    = (const float*)d_in[13];
    const float* fe_out_b    = (const float*)d_in[14];
    const float* g1_lin_w    = (const float*)d_in[15];
    const float* g1_att_src  = (const float*)d_in[16];
    const float* g1_att_dst  = (const float*)d_in[17];
    const float* g1_edge_emb = (const float*)d_in[18];
    const float* g1_lin_edge = (const float*)d_in[19];
    const float* g1_att_edge = (const float*)d_in[20];
    const float* g1_bias     = (const float*)d_in[21];
    const float* g1_res_w    = (const float*)d_in[22];
    const float* g1_res_b    = (const float*)d_in[23];
    const float* g1_ln_g     = (const float*)d_in[24];
    const float* g1_ln_b     = (const float*)d_in[25];
    const float* g2_lin_w    = (const float*)d_in[26];
    const float* g2_att_src  = (const float*)d_in[27];
    const float* g2_att_dst  = (const float*)d_in[28];
    const float* g2_edge_emb = (const float*)d_in[29];
    const float* g2_lin_edge = (const float*)d_in[30];
    const float* g2_att_edge = (const float*)d_in[31];
    const float* g2_bias     = (const float*)d_in[32];
    const float* g2_res_w    = (const float*)d_in[33];
    const float* g2_res_b    = (const float*)d_in[34];
    const float* g2_ln_g     = (const float*)d_in[35];
    const float* g2_ln_b     = (const float*)d_in[36];
    const float* cls_w       = (const float*)d_in[37];
    const float* cls_b       = (const float*)d_in[38];

    const int N = in_sizes[0] / 768;   // 50000
    const int E = in_sizes[1] / 2;     // 800000
    const int* src = edge_index;
    const int* dst = edge_index + E;

    char* wsb = (char*)d_ws;
    size_t off = 0;
    auto alloc = [&](size_t bytes) -> char* {
        char* p = wsb + off;
        off += (bytes + 255) & ~(size_t)255;
        return p;
    };
    float* t1      = (float*)alloc((size_t)N * 64 * 4);
    float* hfe     = (float*)alloc((size_t)N * 64 * 4);
    unsigned short* xs1b = (unsigned short*)alloc((size_t)N * 256 * 2);
    unsigned short* xs2b = (unsigned short*)alloc((size_t)N * 64 * 2);
    float* rp1     = (float*)alloc((size_t)N * 256 * 4);  // res_pre1, then hid1
    float* rp2     = (float*)alloc((size_t)N * 64 * 4);   // res_pre2, then hid2
    float* a_src1  = (float*)alloc((size_t)N * 4 * 4);
    float* a_dst1  = (float*)alloc((size_t)N * 4 * 4);
    float* a_src2  = (float*)alloc((size_t)N * 4);
    float* a_dst2  = (float*)alloc((size_t)N * 4);
    int*   cnt_t   = (int*)alloc((size_t)N * 4 * 4);
    int*   row_off = (int*)alloc((size_t)(N + 1) * 4);
    int*   cursor  = (int*)alloc((size_t)N * 4);
    int*   blk     = (int*)alloc(1024);
    int*   csr_pack= (int*)alloc((size_t)E * 4);
    float* aet1    = (float*)alloc(64);
    float* aet2    = (float*)alloc(64);
    unsigned short* bz_fe1 = (unsigned short*)alloc(768 * 64 * 2);
    unsigned short* bz_p1  = (unsigned short*)alloc(64 * 512 * 2);
    unsigned short* bz_p2  = (unsigned short*)alloc(256 * 128 * 2);

    hipMemsetAsync(cnt_t, 0, (size_t)N * 4 * 4, stream);

    int mb = (N + 63) / 64;   // 782 row-tiles
    int ab = (N + 3) / 4;     // k_att blocks

    k_tables<<<1, 64, 0, stream>>>(g1_edge_emb, g1_lin_edge, g1_att_edge,
                                   g2_edge_emb, g2_lin_edge, g2_att_edge, aet1, aet2);
    k_bswz_fe1<<<48, 256, 0, stream>>>(fe_w1, bz_fe1);
    k_bswz2<64, 256><<<32, 256, 0, stream>>>(g1_lin_w, g1_res_w, bz_p1);
    k_bswz2<256, 64><<<32, 256, 0, stream>>>(g2_lin_w, g2_res_w, bz_p2);
    k_fe1<<<mb, 256, 0, stream>>>(features, bz_fe1, fe_b1, t1, N);
    k_fe2<<<N / 4, 256, 0, stream>>>(t1, fe_w2, fe_b2, ntypes, fe_type_emb, pos,
                                     fe_pos_w, fe_pos_b, fe_out_w, fe_out_b, hfe);
    k_prep_gemm<64, 256><<<dim3(mb, 4), 256, 0, stream>>>(
        hfe, bz_p1, g1_bias, g1_res_b, xs1b, rp1, N);
    k_att<4><<<ab, 256, 0, stream>>>(xs1b, g1_att_src, g1_att_dst, a_src1, a_dst1, N);
    int eblk = (E + 255) / 256;
    int nb = (N + 255) / 256;
    k_count<<<eblk, 256, 0, stream>>>(dst, etypes, cnt_t, E);
    k_scan1<<<nb, 256, 0, stream>>>(cnt_t, row_off, blk, N);
    k_scan2<<<1, 256, 0, stream>>>(blk, nb);
    k_scan3<<<nb, 256, 0, stream>>>(row_off, cursor, blk, N, E);
    k_scatter<<<eblk, 256, 0, stream>>>(src, dst, etypes, cursor, csr_pack, E);
    k_gat1<<<N, 128, 0, stream>>>(xs1b, a_src1, a_dst1, row_off, csr_pack,
                                  cnt_t, aet1, g1_ln_g, g1_ln_b, rp1);
    k_prep_gemm<256, 64><<<dim3(mb, 1), 256, 0, stream>>>(
        rp1, bz_p2, g2_bias, g2_res_b, xs2b, rp2, N);
    k_att<1><<<ab, 256, 0, stream>>>(xs2b, g2_att_src, g2_att_dst, a_src2, a_dst2, N);
    k_gat2<<<N, 64, 0, stream>>>(xs2b, a_src2, a_dst2, row_off, csr_pack,
                                 cnt_t, aet2, g2_ln_g, g2_ln_b, rp2);
    k_cls<<<(out_size + 255) / 256, 256, 0, stream>>>(rp2, aspect, cls_w, cls_b,
                                                      (float*)d_out);
}